// Round 10
// baseline (454.247 us; speedup 1.0000x reference)
//
#include <hip/hip_runtime.h>

#define P_PIX 22500
#define HB 61
#define HSP 22           // pixel splits for hist (48*22=1056 blocks ~ 4.1/CU)
#define PPB 1024         // pixels per hist block (HSP*PPB >= P_PIX)
#define NCHK 8           // 128-px chunks per hist block

typedef float f32x4 __attribute__((ext_vector_type(4)));
typedef _Float16 f16x8 __attribute__((ext_vector_type(8)));

// ---------------------------------------------------------------------------
// MFMA RGB-uv soft histogram (fp16 fragments).  grid (48, HSP), block 256.
// hist[u,v] = sum_p (ku[p,u]*w[p]) * kv[p,v]  == GEMM M=N=64, K=P.
// Phase-2: factored Gaussian arg (du=u-b; -du*du*inv) -- do NOT expand the
// quadratic (fp32 cancellation, r7 post-mortem); exp2 with folded log2e.
// Epilogue also accumulates the per-batch total into hsum[b] (norm fused
// into conv1), one atomicAdd per block.
// ---------------------------------------------------------------------------
__global__ __launch_bounds__(256) void hist_mfma(
    const float* __restrict__ img, const float* __restrict__ su,
    const float* __restrict__ sv, const float* __restrict__ cw,
    const float* __restrict__ msc, float* __restrict__ hist,
    float* __restrict__ hsum)
{
    const int bc = blockIdx.x;
    const int b = bc / 3, c = bc % 3;
    const int split = blockIdx.y;
    const int tid  = threadIdx.x;
    const int wv   = tid >> 6;      // wave id -> owns u-strip [16wv,16wv+16)
    const int lane = tid & 63;
    const int quad = lane >> 4;
    const int mr   = lane & 15;

    __shared__ __align__(16) _Float16 A_lds[8192];   // [pg(16)][u(64)][j(8)]
    __shared__ __align__(16) _Float16 B_lds[8192];
    __shared__ float suu[128], svv[128], sww[128];
    __shared__ float sred[4];

    const float sig_u = su[c], sig_v = sv[c];
    const float L2E = 1.44269504f;
    const float inv_su2 = L2E / (sig_u * sig_u);   // folded log2(e): use exp2
    const float inv_sv2 = L2E / (sig_v * sig_v);
    const float cwc = cw[c];

    // per-thread bin value: lane == bin index for phase-2 writes
    const float ubin = -3.f + 0.1f * (float)lane;

    const bool hasM = (msc != nullptr);
    float m00=0,m01=0,m02=0,m10=0,m11=0,m12=0,m20=0,m21=0,m22=0;
    if (hasM) {
        const float* mp = msc + b * 9;
        m00=mp[0]; m01=mp[1]; m02=mp[2];
        m10=mp[3]; m11=mp[4]; m12=mp[5];
        m20=mp[6]; m21=mp[7]; m22=mp[8];
    }

    const int p0   = split * PPB;
    const int pend = min(p0 + PPB, P_PIX);

    f32x4 acc[4];
#pragma unroll
    for (int nt = 0; nt < 4; ++nt) acc[nt] = (f32x4){0.f, 0.f, 0.f, 0.f};

    for (int chunk = 0; chunk < NCHK; ++chunk) {
        __syncthreads();
        // ---- phase 1: (u, v, weight) for 128 pixels ----
        if (tid < 128) {
            int px = p0 + chunk * 128 + tid;
            float u = 0.f, v = 0.f, wgt = 0.f;
            if (px < pend) {
                const float* ip = img + (size_t)b * 3 * P_PIX + px;
                float r = ip[0], g = ip[P_PIX], bl = ip[2 * P_PIX];
                if (hasM) {
                    float r2 = m00 * r + m01 * g + m02 * bl;
                    float g2 = m10 * r + m11 * g + m12 * bl;
                    float b2 = m20 * r + m21 * g + m22 * bl;
                    r = r2; g = g2; bl = b2;
                }
                r  = fminf(fmaxf(r, 0.f), 1.f);
                g  = fminf(fmaxf(g, 0.f), 1.f);
                bl = fminf(fmaxf(bl, 0.f), 1.f);
                float Iy = sqrtf(r * r + g * g + bl * bl);
                float lr = __logf(r + 1e-6f);
                float lg = __logf(g + 1e-6f);
                float lb = __logf(bl + 1e-6f);
                if (c == 0)      { u = lr - lg; v = lr - lb; }
                else if (c == 1) { u = lg - lr; v = lg - lb; }
                else             { u = lb - lr; v = lb - lg; }
                wgt = Iy * cwc;
            }
            suu[tid] = u; svv[tid] = v; sww[tid] = wgt;
        }
        __syncthreads();
        // ---- phase 2: f16 fragment tables (A = ku*w, B = kv) ----
#pragma unroll
        for (int r = 0; r < 4; ++r) {
            int pg = wv + 4 * r;           // wave-uniform pixel group
            f32x4 u0 = *(const f32x4*)&suu[pg * 8];
            f32x4 u1 = *(const f32x4*)&suu[pg * 8 + 4];
            f32x4 w0 = *(const f32x4*)&sww[pg * 8];
            f32x4 w1 = *(const f32x4*)&sww[pg * 8 + 4];
            f32x4 v0 = *(const f32x4*)&svv[pg * 8];
            f32x4 v1 = *(const f32x4*)&svv[pg * 8 + 4];
            f16x8 av, bv;
#pragma unroll
            for (int j = 0; j < 4; ++j) {
                float du = u0[j] - ubin;
                av[j] = (_Float16)(exp2f(-du * du * inv_su2) * w0[j]);
                float dv = v0[j] - ubin;
                bv[j] = (_Float16)exp2f(-dv * dv * inv_sv2);
            }
#pragma unroll
            for (int j = 0; j < 4; ++j) {
                float du = u1[j] - ubin;
                av[4 + j] = (_Float16)(exp2f(-du * du * inv_su2) * w1[j]);
                float dv = v1[j] - ubin;
                bv[4 + j] = (_Float16)exp2f(-dv * dv * inv_sv2);
            }
            *(f16x8*)&A_lds[(pg * 64 + lane) * 8] = av;
            *(f16x8*)&B_lds[(pg * 64 + lane) * 8] = bv;
        }
        __syncthreads();
        // ---- phase 3: MFMA ----
#pragma unroll
        for (int kk = 0; kk < 4; ++kk) {
            int pgq = kk * 4 + quad;
            f16x8 av = *(const f16x8*)&A_lds[(pgq * 64 + wv * 16 + mr) * 8];
#pragma unroll
            for (int nt = 0; nt < 4; ++nt) {
                f16x8 bvv = *(const f16x8*)&B_lds[(pgq * 64 + nt * 16 + mr) * 8];
                acc[nt] = __builtin_amdgcn_mfma_f32_16x16x32_f16(av, bvv, acc[nt], 0, 0, 0);
            }
        }
    }

    // epilogue: bin atomics + per-batch partial sum
    float* hp = hist + (size_t)bc * HB * HB;
    float lsum = 0.f;
#pragma unroll
    for (int nt = 0; nt < 4; ++nt) {
        int v = nt * 16 + mr;
        if (v >= HB) continue;
#pragma unroll
        for (int r = 0; r < 4; ++r) {
            int u = wv * 16 + quad * 4 + r;
            if (u < HB) { atomicAdd(&hp[u * HB + v], acc[nt][r]); lsum += acc[nt][r]; }
        }
    }
    for (int off = 32; off; off >>= 1) lsum += __shfl_down(lsum, off, 64);
    if (lane == 0) sred[wv] = lsum;
    __syncthreads();
    if (tid == 0) atomicAdd(&hsum[b], sred[0] + sred[1] + sred[2] + sred[3]);
}

// ---------------------------------------------------------------------------
// conv1 as implicit-GEMM MFMA: M=841 sp, N=128 co, K=75 (pad 96).
// grid (16, 7), block 256.  A=weights (global f16), B=activations (LDS,
// gathered from fp32 hist, scaled by 1/(hsum+eps) -- norm fused here).
// Bias+ReLU fused; writes f16 o1 directly.
// ---------------------------------------------------------------------------
__global__ __launch_bounds__(256) void conv1_mfma(
    const float* __restrict__ hist,     // [B][3][3721] UNnormalized
    const float* __restrict__ hsum,     // [B]
    const _Float16* __restrict__ w1h,   // [128][96] (zero-padded)
    const float* __restrict__ bias,     // [128]
    _Float16* __restrict__ out)         // [B][128][841]
{
    const int b    = blockIdx.x;
    const int m0   = blockIdx.y * 128;
    const int tid  = threadIdx.x;
    const int wv   = tid >> 6;
    const int lane = tid & 63;
    const int quad = lane >> 4;
    const int mr   = lane & 15;

    __shared__ __align__(16) _Float16 A_lds[128 * 96];   // [kg(12)][m(128)][8]

    const float sc = 1.f / (hsum[b] + 1e-6f);
    const float* inb = hist + (size_t)b * 3 * 3721;

    // stage activations into fragment layout (normalize on the fly)
    for (int slot = tid; slot < 1536; slot += 256) {
        int m  = slot & 127;
        int kg = slot >> 7;
        int mg = m0 + m;
        bool mok = (mg < 841);
        int oh = mok ? mg / 29 : 0;
        int ow = mok ? mg % 29 : 0;
        const float* pbase = inb + (oh * 2) * 61 + (ow * 2);
        f16x8 av;
#pragma unroll
        for (int j = 0; j < 8; ++j) {
            int k = kg * 8 + j;
            float x = 0.f;
            if (mok && k < 75) {
                int ci = k / 25, r = k % 25;
                int kh = r / 5, kw = r % 5;
                x = pbase[ci * 3721 + kh * 61 + kw] * sc;
            }
            av[j] = (_Float16)x;
        }
        *(f16x8*)&A_lds[(kg * 128 + m) * 8] = av;
    }
    __syncthreads();

    // weight fragments (A operand)
    f16x8 wf[3][2];
#pragma unroll
    for (int ks = 0; ks < 3; ++ks)
#pragma unroll
        for (int nt = 0; nt < 2; ++nt) {
            int co = (wv * 2 + nt) * 16 + mr;
            wf[ks][nt] = *(const f16x8*)&w1h[co * 96 + ks * 32 + quad * 8];
        }

    f32x4 acc[8][2];
#pragma unroll
    for (int mt = 0; mt < 8; ++mt)
#pragma unroll
        for (int nt = 0; nt < 2; ++nt) acc[mt][nt] = (f32x4){0.f, 0.f, 0.f, 0.f};

#pragma unroll
    for (int ks = 0; ks < 3; ++ks)
#pragma unroll
        for (int mt = 0; mt < 8; ++mt) {
            f16x8 bv = *(const f16x8*)&A_lds[((ks * 4 + quad) * 128 + mt * 16 + mr) * 8];
#pragma unroll
            for (int nt = 0; nt < 2; ++nt)
                acc[mt][nt] = __builtin_amdgcn_mfma_f32_16x16x32_f16(wf[ks][nt], bv, acc[mt][nt], 0, 0, 0);
        }

    // epilogue: D[row=co local][col=sp local]; bias + relu, f16 store
#pragma unroll
    for (int mt = 0; mt < 8; ++mt) {
        int sp = m0 + mt * 16 + mr;
        if (sp >= 841) continue;
#pragma unroll
        for (int nt = 0; nt < 2; ++nt) {
#pragma unroll
            for (int r = 0; r < 4; ++r) {
                int co = (wv * 2 + nt) * 16 + quad * 4 + r;
                float y = acc[mt][nt][r] + bias[co];
                out[((size_t)b * 128 + co) * 841 + sp] = (_Float16)fmaxf(y, 0.f);
            }
        }
    }
}

// ---------------------------------------------------------------------------
// conv2/conv3: implicit-GEMM MFMA (fp16 in, fp32 acc).
// grid (B, COUT/NPB, KSPL), block 256 (4 waves).  A=weights, B=activations;
// split-K partials to private slabs; reduce+bias+relu afterwards.
// ---------------------------------------------------------------------------
template<int CIN, int COUT, int Kk, int S, int IN, int OUT,
         int NPB, int KSPL, int KCH>
__global__ __launch_bounds__(256) void conv_mfma(
    const _Float16* __restrict__ in_h,   // [B][CIN][IN*IN]
    const _Float16* __restrict__ w_h,    // [COUT][CIN*KK]
    float* __restrict__ out)             // [KSPL][B][COUT][OUT*OUT]
{
    constexpr int KK   = Kk * Kk;
    constexpr int OSZ  = OUT * OUT;
    constexpr int MT   = (OSZ + 15) / 16;   // sp-tiles
    constexpr int MP   = MT * 16;
    constexpr int KTOT = CIN * KK;
    constexpr int KC   = KTOT / KSPL;       // k per block
    constexpr int NCHUNK = KC / KCH;
    constexpr int NT   = NPB / 64;          // co-tiles per wave
    constexpr int KSN  = KCH / 32;          // mfma k-steps per chunk
    constexpr int SLOTS = MP * (KCH / 8);

    const int b   = blockIdx.x;
    const int co0 = blockIdx.y * NPB;
    const int k00 = blockIdx.z * KC;
    const int tid  = threadIdx.x;
    const int wv   = tid >> 6;
    const int lane = tid & 63;
    const int quad = lane >> 4;
    const int mr   = lane & 15;

    __shared__ __align__(16) _Float16 A_lds[MP * KCH];

    const _Float16* inb = in_h + (size_t)b * CIN * (IN * IN);
    float* outp = out + (size_t)blockIdx.z * gridDim.x * COUT * OSZ;

    f32x4 acc[MT][NT];
#pragma unroll
    for (int mt = 0; mt < MT; ++mt)
#pragma unroll
        for (int nt = 0; nt < NT; ++nt) acc[mt][nt] = (f32x4){0.f, 0.f, 0.f, 0.f};

    for (int ch = 0; ch < NCHUNK; ++ch) {
        const int k0 = k00 + ch * KCH;
        __syncthreads();
        for (int slot = tid; slot < SLOTS; slot += 256) {
            int m  = slot % MP;
            int kg = slot / MP;
            bool mok = (m < OSZ);
            int oh = mok ? m / OUT : 0;
            int ow = mok ? m % OUT : 0;
            int kbase = k0 + kg * 8;
            f16x8 av;
#pragma unroll
            for (int j = 0; j < 8; ++j) {
                int k  = kbase + j;
                int ci = k / KK;
                int r  = k % KK;
                int kh = r / Kk, kw = r % Kk;
                _Float16 x = (_Float16)0.f;
                if (mok) x = inb[ci * (IN * IN) + (oh * S + kh) * IN + (ow * S + kw)];
                av[j] = x;
            }
            *(f16x8*)&A_lds[(kg * MP + m) * 8] = av;
        }
        __syncthreads();
        f16x8 wf[KSN][NT];
#pragma unroll
        for (int ks = 0; ks < KSN; ++ks)
#pragma unroll
            for (int nt = 0; nt < NT; ++nt) {
                int co = co0 + (wv * NT + nt) * 16 + mr;
                wf[ks][nt] = *(const f16x8*)&w_h[(size_t)co * KTOT + k0 + ks * 32 + quad * 8];
            }
#pragma unroll
        for (int ks = 0; ks < KSN; ++ks) {
#pragma unroll
            for (int mt = 0; mt < MT; ++mt) {
                f16x8 bv = *(const f16x8*)&A_lds[((ks * 4 + quad) * MP + mt * 16 + mr) * 8];
#pragma unroll
                for (int nt = 0; nt < NT; ++nt)
                    acc[mt][nt] = __builtin_amdgcn_mfma_f32_16x16x32_f16(wf[ks][nt], bv, acc[mt][nt], 0, 0, 0);
            }
        }
    }

#pragma unroll
    for (int mt = 0; mt < MT; ++mt) {
        int sp = mt * 16 + mr;
        if (sp >= OSZ) continue;
#pragma unroll
        for (int nt = 0; nt < NT; ++nt) {
#pragma unroll
            for (int r = 0; r < 4; ++r) {
                int co = co0 + (wv * NT + nt) * 16 + quad * 4 + r;
                outp[((size_t)b * COUT + co) * OSZ + sp] = acc[mt][nt][r];
            }
        }
    }
}

// ---------------------------------------------------------------------------
// sum KSPL split-K partials + bias + ReLU -> f16 out.
// ---------------------------------------------------------------------------
__global__ __launch_bounds__(256) void reduce_bias_relu_f16(
    const float* __restrict__ p, const float* __restrict__ bias,
    _Float16* __restrict__ out, int cout, int osz, int total, int kspl)
{
    for (int i = blockIdx.x * 256 + threadIdx.x; i < total; i += gridDim.x * 256) {
        float s = 0.f;
        for (int ks = 0; ks < kspl; ++ks) s += p[(size_t)ks * total + i];
        int co = (i / osz) % cout;
        out[i] = (_Float16)fmaxf(s + bias[co], 0.f);
    }
}

// ---------------------------------------------------------------------------
// sum KSPL split-K partials + bias + ReLU -> fp32 out.
// ---------------------------------------------------------------------------
__global__ __launch_bounds__(256) void reduce_bias_relu(
    const float* __restrict__ p, const float* __restrict__ bias,
    float* __restrict__ out, int cout, int osz, int total, int kspl)
{
    for (int i = blockIdx.x * 256 + threadIdx.x; i < total; i += gridDim.x * 256) {
        float s = 0.f;
        for (int ks = 0; ks < kspl; ++ks) s += p[(size_t)ks * total + i];
        int co = (i / osz) % cout;
        out[i] = fmaxf(s + bias[co], 0.f);
    }
}

// ---------------------------------------------------------------------------
// fp32 -> f16 cast (weight prep).
// ---------------------------------------------------------------------------
__global__ __launch_bounds__(256) void cast_f16(
    const float* __restrict__ src, _Float16* __restrict__ dst, int n)
{
    for (int i = blockIdx.x * 256 + threadIdx.x; i < n; i += gridDim.x * 256)
        dst[i] = (_Float16)src[i];
}

// ---------------------------------------------------------------------------
// w1 cast with K-pad 75 -> 96 (both branches in one dispatch, grid.y picks).
// ---------------------------------------------------------------------------
__global__ __launch_bounds__(256) void cast_w1_pad(
    const float* __restrict__ s0, _Float16* __restrict__ d0,
    const float* __restrict__ s1, _Float16* __restrict__ d1)
{
    const float* s = blockIdx.y ? s1 : s0;
    _Float16* d = blockIdx.y ? d1 : d0;
    int i = blockIdx.x * 256 + threadIdx.x;
    if (i < 128 * 96) {
        int co = i / 96, k = i % 96;
        d[i] = (k < 75) ? (_Float16)s[co * 75 + k] : (_Float16)0.f;
    }
}

// ---------------------------------------------------------------------------
// FC split-K: partial dot -> atomicAdd into out[b*NO+o] (pre-zeroed).
// ---------------------------------------------------------------------------
__global__ __launch_bounds__(256) void fc_atomic(
    const float* __restrict__ z, const float* __restrict__ fcw,
    float* __restrict__ out, int Kdim, int NO, int KSPL)
{
    const int b = blockIdx.x, o = blockIdx.y, ks = blockIdx.z;
    const int kchunk = Kdim / KSPL;
    const int k0 = ks * kchunk;
    const float* zp = z + (size_t)b * Kdim + k0;
    const float* wp = fcw + (size_t)o * Kdim + k0;
    float s = 0.f;
    for (int k = threadIdx.x; k < kchunk; k += 256) s = fmaf(zp[k], wp[k], s);
    __shared__ float red[4];
    for (int off = 32; off; off >>= 1) s += __shfl_down(s, off, 64);
    if ((threadIdx.x & 63) == 0) red[threadIdx.x >> 6] = s;
    __syncthreads();
    if (threadIdx.x == 0)
        atomicAdd(&out[(size_t)b * NO + o], red[0] + red[1] + red[2] + red[3]);
}

// ---------------------------------------------------------------------------
// m = reshape(|h|,3,3)^T; n = max L1 row norm + 1e-4; msc = m / n.
// ---------------------------------------------------------------------------
__global__ void build_m(const float* __restrict__ h, float* __restrict__ msc)
{
    int b = threadIdx.x;
    if (b < 16) {
        float m[9];
#pragma unroll
        for (int i = 0; i < 3; ++i)
#pragma unroll
            for (int j = 0; j < 3; ++j) m[i * 3 + j] = fabsf(h[b * 9 + j * 3 + i]);
        float n = 0.f;
#pragma unroll
        for (int i = 0; i < 3; ++i) {
            float r = m[i * 3] + m[i * 3 + 1] + m[i * 3 + 2];
            n = fmaxf(n, r);
        }
        n += 1e-4f;
        float inv = 1.f / n;
#pragma unroll
        for (int k = 0; k < 9; ++k) msc[b * 9 + k] = m[k] * inv;
    }
}

// ---------------------------------------------------------------------------
// est[b] = inv(msc[b]) @ |ill[b]|
// ---------------------------------------------------------------------------
__global__ void final_est(const float* __restrict__ msc, const float* __restrict__ ill,
                          float* __restrict__ out)
{
    int bidx = threadIdx.x;
    if (bidx < 16) {
        const float* m = msc + bidx * 9;
        float a = m[0], b = m[1], c = m[2];
        float d = m[3], e = m[4], f = m[5];
        float g = m[6], h = m[7], i = m[8];
        float A = e * i - f * h, B = f * g - d * i, C = d * h - e * g;
        float D = c * h - b * i, E = a * i - c * g, F = b * g - a * h;
        float G = b * f - c * e, H = c * d - a * f, I = a * e - b * d;
        float det = a * A + b * B + c * C;
        float inv_det = 1.f / det;
        float x0 = fabsf(ill[bidx * 3 + 0]);
        float x1 = fabsf(ill[bidx * 3 + 1]);
        float x2 = fabsf(ill[bidx * 3 + 2]);
        out[bidx * 3 + 0] = (A * x0 + D * x1 + G * x2) * inv_det;
        out[bidx * 3 + 1] = (B * x0 + E * x1 + H * x2) * inv_det;
        out[bidx * 3 + 2] = (C * x0 + F * x1 + I * x2) * inv_det;
    }
}

extern "C" void kernel_launch(void* const* d_in, const int* in_sizes, int n_in,
                              void* d_out, int out_size, void* d_ws, size_t ws_size,
                              hipStream_t stream)
{
    (void)in_sizes; (void)n_in; (void)out_size; (void)ws_size;
    const float* image = (const float*)d_in[0];
    const float* su_s  = (const float*)d_in[1];
    const float* sv_s  = (const float*)d_in[2];
    const float* c_s   = (const float*)d_in[3];
    const float* w1_s  = (const float*)d_in[4];
    const float* b1_s  = (const float*)d_in[5];
    const float* w2_s  = (const float*)d_in[6];
    const float* b2_s  = (const float*)d_in[7];
    const float* w3_s  = (const float*)d_in[8];
    const float* b3_s  = (const float*)d_in[9];
    const float* fc_s  = (const float*)d_in[10];
    const float* su_i  = (const float*)d_in[11];
    const float* sv_i  = (const float*)d_in[12];
    const float* c_i   = (const float*)d_in[13];
    const float* w1_i  = (const float*)d_in[14];
    const float* b1_i  = (const float*)d_in[15];
    const float* w2_i  = (const float*)d_in[16];
    const float* b2_i  = (const float*)d_in[17];
    const float* w3_i  = (const float*)d_in[18];
    const float* b3_i  = (const float*)d_in[19];
    const float* fc_i  = (const float*)d_in[20];

    // ---- workspace layout: cumulative pointer arithmetic ONLY ----
    float* W     = (float*)d_ws;
    float* hist  = W;                         // 16*3*61*61 = 178608 f
    float* o3    = hist + 178608;             // 16*512*169 = 1384448 f
    float* hd    = o3 + 1384448;              // 144 f
    float* hsum  = hd + 144;                  // 16 f (memset together w/ hd)
    float* msc   = hsum + 16;                 // 144 f (NOT re-zeroed)
    float* p2    = msc + 144;                 // 4*16*256*196 = 3211264 f
    float* p3    = p2 + 3211264;              // 4*16*512*169 = 5537792 f
    _Float16* o1h   = (_Float16*)(p3 + 5537792);
    _Float16* o2h   = o1h   + 1722368;        // o1h: 16*128*841 halfs
    _Float16* w2h_s = o2h   + 802816;         // o2h: 16*256*196 halfs
    _Float16* w3h_s = w2h_s + 294912;         // w2h: 256*1152 halfs
    _Float16* w2h_i = w3h_s + 524288;         // w3h: 512*1024 halfs
    _Float16* w3h_i = w2h_i + 294912;
    _Float16* w1h_s = w3h_i + 524288;         // after w3h_i's FULL extent
    _Float16* w1h_i = w1h_s + 12288;          // w1h: 128*96 halfs

    const size_t HIST_BYTES = 178608u * sizeof(float);
    const int FCK = 512 * 13 * 13;
    const int O2_TOT = 16 * 256 * 196;
    const int O3_TOT = 16 * 512 * 169;

    // ---- weight prep (f16 casts) ----
    cast_w1_pad<<<dim3(48, 2), 256, 0, stream>>>(w1_s, w1h_s, w1_i, w1h_i);
    cast_f16<<<288, 256, 0, stream>>>(w2_s, w2h_s, 256 * 1152);
    cast_f16<<<512, 256, 0, stream>>>(w3_s, w3h_s, 512 * 1024);
    cast_f16<<<288, 256, 0, stream>>>(w2_i, w2h_i, 256 * 1152);
    cast_f16<<<512, 256, 0, stream>>>(w3_i, w3h_i, 512 * 1024);

    // ================= sensor branch =================
    hipMemsetAsync(hist, 0, HIST_BYTES, stream);
    hipMemsetAsync(hd, 0, 160 * 4, stream);   // hd(144) + hsum(16)
    hist_mfma<<<dim3(48, HSP), 256, 0, stream>>>(image, su_s, sv_s, c_s, nullptr, hist, hsum);
    conv1_mfma<<<dim3(16, 7), 256, 0, stream>>>(hist, hsum, w1h_s, b1_s, o1h);
    conv_mfma<128, 256, 3, 2, 29, 14, 128, 4, 96><<<dim3(16, 2, 4), 256, 0, stream>>>(o1h, w2h_s, p2);
    reduce_bias_relu_f16<<<1024, 256, 0, stream>>>(p2, b2_s, o2h, 256, 196, O2_TOT, 4);
    conv_mfma<256, 512, 2, 1, 14, 13, 128, 4, 64><<<dim3(16, 4, 4), 256, 0, stream>>>(o2h, w3h_s, p3);
    reduce_bias_relu<<<1024, 256, 0, stream>>>(p3, b3_s, o3, 512, 169, O3_TOT, 4);
    fc_atomic<<<dim3(16, 9, 8), 256, 0, stream>>>(o3, fc_s, hd, FCK, 9, 8);
    build_m<<<1, 64, 0, stream>>>(hd, msc);

    // ================= illuminant branch =================
    hipMemsetAsync(hist, 0, HIST_BYTES, stream);
    hipMemsetAsync(hd, 0, 160 * 4, stream);   // hd + hsum; msc preserved
    hist_mfma<<<dim3(48, HSP), 256, 0, stream>>>(image, su_i, sv_i, c_i, msc, hist, hsum);
    conv1_mfma<<<dim3(16, 7), 256, 0, stream>>>(hist, hsum, w1h_i, b1_i, o1h);
    conv_mfma<128, 256, 3, 2, 29, 14, 128, 4, 96><<<dim3(16, 2, 4), 256, 0, stream>>>(o1h, w2h_i, p2);
    reduce_bias_relu_f16<<<1024, 256, 0, stream>>>(p2, b2_i, o2h, 256, 196, O2_TOT, 4);
    conv_mfma<256, 512, 2, 1, 14, 13, 128, 4, 64><<<dim3(16, 4, 4), 256, 0, stream>>>(o2h, w3h_i, p3);
    reduce_bias_relu<<<1024, 256, 0, stream>>>(p3, b3_i, o3, 512, 169, O3_TOT, 4);
    fc_atomic<<<dim3(16, 3, 8), 256, 0, stream>>>(o3, fc_i, hd, FCK, 3, 8);
    final_est<<<1, 64, 0, stream>>>(msc, hd, (float*)d_out);
}

// Round 11
// 405.212 us; speedup vs baseline: 1.1210x; 1.1210x over previous
//
#include <hip/hip_runtime.h>

#define P_PIX 22500
#define HB 61
#define HSP 21           // pixel splits for hist (48*21=1008 blocks ~ 3.94/CU)
#define PPB 1152         // pixels per hist block (HSP*PPB=24192 >= P_PIX)
#define NCHK 9           // 128-px chunks per hist block

typedef float f32x4 __attribute__((ext_vector_type(4)));
typedef _Float16 f16x8 __attribute__((ext_vector_type(8)));

// ---------------------------------------------------------------------------
// MFMA RGB-uv soft histogram (fp16 fragments).  grid (48, HSP), block 256.
// hist[u,v] = sum_p (ku[p,u]*w[p]) * kv[p,v]  == GEMM M=N=64, K=P.
// Factored Gaussian arg (r7: never expand the quadratic); __expf (r10: libm
// exp2f regressed).  Epilogue: plain stores to a private 64x64 slab per
// block -- NO atomics (r10: atomic traffic scaled with splits and dominated).
// ---------------------------------------------------------------------------
__global__ __launch_bounds__(256) void hist_mfma(
    const float* __restrict__ img, const float* __restrict__ su,
    const float* __restrict__ sv, const float* __restrict__ cw,
    const float* __restrict__ msc, float* __restrict__ hpart)
{
    const int bc = blockIdx.x;
    const int b = bc / 3, c = bc % 3;
    const int split = blockIdx.y;
    const int tid  = threadIdx.x;
    const int wv   = tid >> 6;      // wave id -> owns u-strip [16wv,16wv+16)
    const int lane = tid & 63;
    const int quad = lane >> 4;
    const int mr   = lane & 15;

    __shared__ __align__(16) _Float16 A_lds[8192];   // [pg(16)][u(64)][j(8)]
    __shared__ __align__(16) _Float16 B_lds[8192];
    __shared__ float suu[128], svv[128], sww[128];

    const float sig_u = su[c], sig_v = sv[c];
    const float inv_su2 = 1.f / (sig_u * sig_u);
    const float inv_sv2 = 1.f / (sig_v * sig_v);
    const float cwc = cw[c];

    // per-thread bin value: lane == bin index for phase-2 writes
    const float ubin = -3.f + 0.1f * (float)lane;

    const bool hasM = (msc != nullptr);
    float m00=0,m01=0,m02=0,m10=0,m11=0,m12=0,m20=0,m21=0,m22=0;
    if (hasM) {
        const float* mp = msc + b * 9;
        m00=mp[0]; m01=mp[1]; m02=mp[2];
        m10=mp[3]; m11=mp[4]; m12=mp[5];
        m20=mp[6]; m21=mp[7]; m22=mp[8];
    }

    const int p0   = split * PPB;
    const int pend = min(p0 + PPB, P_PIX);

    f32x4 acc[4];
#pragma unroll
    for (int nt = 0; nt < 4; ++nt) acc[nt] = (f32x4){0.f, 0.f, 0.f, 0.f};

    for (int chunk = 0; chunk < NCHK; ++chunk) {
        __syncthreads();
        // ---- phase 1: (u, v, weight) for 128 pixels ----
        if (tid < 128) {
            int px = p0 + chunk * 128 + tid;
            float u = 0.f, v = 0.f, wgt = 0.f;
            if (px < pend) {
                const float* ip = img + (size_t)b * 3 * P_PIX + px;
                float r = ip[0], g = ip[P_PIX], bl = ip[2 * P_PIX];
                if (hasM) {
                    float r2 = m00 * r + m01 * g + m02 * bl;
                    float g2 = m10 * r + m11 * g + m12 * bl;
                    float b2 = m20 * r + m21 * g + m22 * bl;
                    r = r2; g = g2; bl = b2;
                }
                r  = fminf(fmaxf(r, 0.f), 1.f);
                g  = fminf(fmaxf(g, 0.f), 1.f);
                bl = fminf(fmaxf(bl, 0.f), 1.f);
                float Iy = sqrtf(r * r + g * g + bl * bl);
                float lr = __logf(r + 1e-6f);
                float lg = __logf(g + 1e-6f);
                float lb = __logf(bl + 1e-6f);
                if (c == 0)      { u = lr - lg; v = lr - lb; }
                else if (c == 1) { u = lg - lr; v = lg - lb; }
                else             { u = lb - lr; v = lb - lg; }
                wgt = Iy * cwc;
            }
            suu[tid] = u; svv[tid] = v; sww[tid] = wgt;
        }
        __syncthreads();
        // ---- phase 2: f16 fragment tables (A = ku*w, B = kv) ----
#pragma unroll
        for (int r = 0; r < 4; ++r) {
            int pg = wv + 4 * r;           // wave-uniform pixel group
            f32x4 u0 = *(const f32x4*)&suu[pg * 8];
            f32x4 u1 = *(const f32x4*)&suu[pg * 8 + 4];
            f32x4 w0 = *(const f32x4*)&sww[pg * 8];
            f32x4 w1 = *(const f32x4*)&sww[pg * 8 + 4];
            f32x4 v0 = *(const f32x4*)&svv[pg * 8];
            f32x4 v1 = *(const f32x4*)&svv[pg * 8 + 4];
            f16x8 av, bv;
#pragma unroll
            for (int j = 0; j < 4; ++j) {
                float du = u0[j] - ubin;
                av[j] = (_Float16)(__expf(-du * du * inv_su2) * w0[j]);
                float dv = v0[j] - ubin;
                bv[j] = (_Float16)__expf(-dv * dv * inv_sv2);
            }
#pragma unroll
            for (int j = 0; j < 4; ++j) {
                float du = u1[j] - ubin;
                av[4 + j] = (_Float16)(__expf(-du * du * inv_su2) * w1[j]);
                float dv = v1[j] - ubin;
                bv[4 + j] = (_Float16)__expf(-dv * dv * inv_sv2);
            }
            *(f16x8*)&A_lds[(pg * 64 + lane) * 8] = av;
            *(f16x8*)&B_lds[(pg * 64 + lane) * 8] = bv;
        }
        __syncthreads();
        // ---- phase 3: MFMA ----
#pragma unroll
        for (int kk = 0; kk < 4; ++kk) {
            int pgq = kk * 4 + quad;
            f16x8 av = *(const f16x8*)&A_lds[(pgq * 64 + wv * 16 + mr) * 8];
#pragma unroll
            for (int nt = 0; nt < 4; ++nt) {
                f16x8 bvv = *(const f16x8*)&B_lds[(pgq * 64 + nt * 16 + mr) * 8];
                acc[nt] = __builtin_amdgcn_mfma_f32_16x16x32_f16(av, bvv, acc[nt], 0, 0, 0);
            }
        }
    }

    // epilogue: plain stores to private slab (full 64x64, pads included)
    float* hp = hpart + ((size_t)bc * HSP + split) * 4096;
#pragma unroll
    for (int nt = 0; nt < 4; ++nt) {
        int v = nt * 16 + mr;
#pragma unroll
        for (int r = 0; r < 4; ++r) {
            int u = wv * 16 + quad * 4 + r;
            hp[u * 64 + v] = acc[nt][r];
        }
    }
}

// ---------------------------------------------------------------------------
// Sum HSP slabs -> hist[bc][61*61]; per-(b,c) total -> hsum3[bc].
// grid (48, 4), block 256; each (bc, part) handles 1024 of 4096 positions.
// ---------------------------------------------------------------------------
__global__ __launch_bounds__(256) void reduce_hist(
    const float* __restrict__ hpart, float* __restrict__ hist,
    float* __restrict__ hsum3)
{
    const int bc = blockIdx.x;
    const int part = blockIdx.y;
    const int tid = threadIdx.x;
    const float* base = hpart + (size_t)bc * HSP * 4096;
    float lsum = 0.f;
#pragma unroll
    for (int t = 0; t < 4; ++t) {
        int idx = part * 1024 + t * 256 + tid;
        int u = idx >> 6, v = idx & 63;
        float s = 0.f;
        for (int sp = 0; sp < HSP; ++sp) s += base[sp * 4096 + idx];
        if (u < HB && v < HB) {
            hist[(size_t)bc * (HB * HB) + u * HB + v] = s;
            lsum += s;
        }
    }
    __shared__ float red[4];
    for (int off = 32; off; off >>= 1) lsum += __shfl_down(lsum, off, 64);
    if ((tid & 63) == 0) red[tid >> 6] = lsum;
    __syncthreads();
    if (tid == 0) atomicAdd(&hsum3[bc], red[0] + red[1] + red[2] + red[3]);
}

// ---------------------------------------------------------------------------
// conv1 as implicit-GEMM MFMA: M=841 sp, N=128 co, K=75 (pad 96).
// grid (16, 7), block 256.  A=weights (global f16), B=activations (LDS,
// gathered from fp32 hist, scaled by 1/(sum+eps) -- norm fused here).
// Bias+ReLU fused; writes f16 o1 directly.
// ---------------------------------------------------------------------------
__global__ __launch_bounds__(256) void conv1_mfma(
    const float* __restrict__ hist,     // [B][3][3721] UNnormalized
    const float* __restrict__ hsum3,    // [48] per-(b,c) sums
    const _Float16* __restrict__ w1h,   // [128][96] (zero-padded)
    const float* __restrict__ bias,     // [128]
    _Float16* __restrict__ out)         // [B][128][841]
{
    const int b    = blockIdx.x;
    const int m0   = blockIdx.y * 128;
    const int tid  = threadIdx.x;
    const int wv   = tid >> 6;
    const int lane = tid & 63;
    const int quad = lane >> 4;
    const int mr   = lane & 15;

    __shared__ __align__(16) _Float16 A_lds[128 * 96];   // [kg(12)][m(128)][8]

    const float sc = 1.f / (hsum3[b * 3] + hsum3[b * 3 + 1] + hsum3[b * 3 + 2] + 1e-6f);
    const float* inb = hist + (size_t)b * 3 * 3721;

    // stage activations into fragment layout (normalize on the fly)
    for (int slot = tid; slot < 1536; slot += 256) {
        int m  = slot & 127;
        int kg = slot >> 7;
        int mg = m0 + m;
        bool mok = (mg < 841);
        int oh = mok ? mg / 29 : 0;
        int ow = mok ? mg % 29 : 0;
        const float* pbase = inb + (oh * 2) * 61 + (ow * 2);
        f16x8 av;
#pragma unroll
        for (int j = 0; j < 8; ++j) {
            int k = kg * 8 + j;
            float x = 0.f;
            if (mok && k < 75) {
                int ci = k / 25, r = k % 25;
                int kh = r / 5, kw = r % 5;
                x = pbase[ci * 3721 + kh * 61 + kw] * sc;
            }
            av[j] = (_Float16)x;
        }
        *(f16x8*)&A_lds[(kg * 128 + m) * 8] = av;
    }
    __syncthreads();

    // weight fragments (A operand)
    f16x8 wf[3][2];
#pragma unroll
    for (int ks = 0; ks < 3; ++ks)
#pragma unroll
        for (int nt = 0; nt < 2; ++nt) {
            int co = (wv * 2 + nt) * 16 + mr;
            wf[ks][nt] = *(const f16x8*)&w1h[co * 96 + ks * 32 + quad * 8];
        }

    f32x4 acc[8][2];
#pragma unroll
    for (int mt = 0; mt < 8; ++mt)
#pragma unroll
        for (int nt = 0; nt < 2; ++nt) acc[mt][nt] = (f32x4){0.f, 0.f, 0.f, 0.f};

#pragma unroll
    for (int ks = 0; ks < 3; ++ks)
#pragma unroll
        for (int mt = 0; mt < 8; ++mt) {
            f16x8 bv = *(const f16x8*)&A_lds[((ks * 4 + quad) * 128 + mt * 16 + mr) * 8];
#pragma unroll
            for (int nt = 0; nt < 2; ++nt)
                acc[mt][nt] = __builtin_amdgcn_mfma_f32_16x16x32_f16(wf[ks][nt], bv, acc[mt][nt], 0, 0, 0);
        }

    // epilogue: D[row=co local][col=sp local]; bias + relu, f16 store
#pragma unroll
    for (int mt = 0; mt < 8; ++mt) {
        int sp = m0 + mt * 16 + mr;
        if (sp >= 841) continue;
#pragma unroll
        for (int nt = 0; nt < 2; ++nt) {
#pragma unroll
            for (int r = 0; r < 4; ++r) {
                int co = (wv * 2 + nt) * 16 + quad * 4 + r;
                float y = acc[mt][nt][r] + bias[co];
                out[((size_t)b * 128 + co) * 841 + sp] = (_Float16)fmaxf(y, 0.f);
            }
        }
    }
}

// ---------------------------------------------------------------------------
// conv2/conv3: implicit-GEMM MFMA (fp16 in, fp32 acc).
// grid (B, COUT/NPB, KSPL), block 256 (4 waves).  A=weights, B=activations;
// split-K partials to private slabs; reduce+bias+relu afterwards.
// ---------------------------------------------------------------------------
template<int CIN, int COUT, int Kk, int S, int IN, int OUT,
         int NPB, int KSPL, int KCH>
__global__ __launch_bounds__(256) void conv_mfma(
    const _Float16* __restrict__ in_h,   // [B][CIN][IN*IN]
    const _Float16* __restrict__ w_h,    // [COUT][CIN*KK]
    float* __restrict__ out)             // [KSPL][B][COUT][OUT*OUT]
{
    constexpr int KK   = Kk * Kk;
    constexpr int OSZ  = OUT * OUT;
    constexpr int MT   = (OSZ + 15) / 16;   // sp-tiles
    constexpr int MP   = MT * 16;
    constexpr int KTOT = CIN * KK;
    constexpr int KC   = KTOT / KSPL;       // k per block
    constexpr int NCHUNK = KC / KCH;
    constexpr int NT   = NPB / 64;          // co-tiles per wave
    constexpr int KSN  = KCH / 32;          // mfma k-steps per chunk
    constexpr int SLOTS = MP * (KCH / 8);

    const int b   = blockIdx.x;
    const int co0 = blockIdx.y * NPB;
    const int k00 = blockIdx.z * KC;
    const int tid  = threadIdx.x;
    const int wv   = tid >> 6;
    const int lane = tid & 63;
    const int quad = lane >> 4;
    const int mr   = lane & 15;

    __shared__ __align__(16) _Float16 A_lds[MP * KCH];

    const _Float16* inb = in_h + (size_t)b * CIN * (IN * IN);
    float* outp = out + (size_t)blockIdx.z * gridDim.x * COUT * OSZ;

    f32x4 acc[MT][NT];
#pragma unroll
    for (int mt = 0; mt < MT; ++mt)
#pragma unroll
        for (int nt = 0; nt < NT; ++nt) acc[mt][nt] = (f32x4){0.f, 0.f, 0.f, 0.f};

    for (int ch = 0; ch < NCHUNK; ++ch) {
        const int k0 = k00 + ch * KCH;
        __syncthreads();
        for (int slot = tid; slot < SLOTS; slot += 256) {
            int m  = slot % MP;
            int kg = slot / MP;
            bool mok = (m < OSZ);
            int oh = mok ? m / OUT : 0;
            int ow = mok ? m % OUT : 0;
            int kbase = k0 + kg * 8;
            f16x8 av;
#pragma unroll
            for (int j = 0; j < 8; ++j) {
                int k  = kbase + j;
                int ci = k / KK;
                int r  = k % KK;
                int kh = r / Kk, kw = r % Kk;
                _Float16 x = (_Float16)0.f;
                if (mok) x = inb[ci * (IN * IN) + (oh * S + kh) * IN + (ow * S + kw)];
                av[j] = x;
            }
            *(f16x8*)&A_lds[(kg * MP + m) * 8] = av;
        }
        __syncthreads();
        f16x8 wf[KSN][NT];
#pragma unroll
        for (int ks = 0; ks < KSN; ++ks)
#pragma unroll
            for (int nt = 0; nt < NT; ++nt) {
                int co = co0 + (wv * NT + nt) * 16 + mr;
                wf[ks][nt] = *(const f16x8*)&w_h[(size_t)co * KTOT + k0 + ks * 32 + quad * 8];
            }
#pragma unroll
        for (int ks = 0; ks < KSN; ++ks) {
#pragma unroll
            for (int mt = 0; mt < MT; ++mt) {
                f16x8 bv = *(const f16x8*)&A_lds[((ks * 4 + quad) * MP + mt * 16 + mr) * 8];
#pragma unroll
                for (int nt = 0; nt < NT; ++nt)
                    acc[mt][nt] = __builtin_amdgcn_mfma_f32_16x16x32_f16(wf[ks][nt], bv, acc[mt][nt], 0, 0, 0);
            }
        }
    }

#pragma unroll
    for (int mt = 0; mt < MT; ++mt) {
        int sp = mt * 16 + mr;
        if (sp >= OSZ) continue;
#pragma unroll
        for (int nt = 0; nt < NT; ++nt) {
#pragma unroll
            for (int r = 0; r < 4; ++r) {
                int co = co0 + (wv * NT + nt) * 16 + quad * 4 + r;
                outp[((size_t)b * COUT + co) * OSZ + sp] = acc[mt][nt][r];
            }
        }
    }
}

// ---------------------------------------------------------------------------
// sum KSPL split-K partials + bias + ReLU -> f16 out.
// ---------------------------------------------------------------------------
__global__ __launch_bounds__(256) void reduce_bias_relu_f16(
    const float* __restrict__ p, const float* __restrict__ bias,
    _Float16* __restrict__ out, int cout, int osz, int total, int kspl)
{
    for (int i = blockIdx.x * 256 + threadIdx.x; i < total; i += gridDim.x * 256) {
        float s = 0.f;
        for (int ks = 0; ks < kspl; ++ks) s += p[(size_t)ks * total + i];
        int co = (i / osz) % cout;
        out[i] = (_Float16)fmaxf(s + bias[co], 0.f);
    }
}

// ---------------------------------------------------------------------------
// sum KSPL split-K partials + bias + ReLU -> fp32 out.
// ---------------------------------------------------------------------------
__global__ __launch_bounds__(256) void reduce_bias_relu(
    const float* __restrict__ p, const float* __restrict__ bias,
    float* __restrict__ out, int cout, int osz, int total, int kspl)
{
    for (int i = blockIdx.x * 256 + threadIdx.x; i < total; i += gridDim.x * 256) {
        float s = 0.f;
        for (int ks = 0; ks < kspl; ++ks) s += p[(size_t)ks * total + i];
        int co = (i / osz) % cout;
        out[i] = fmaxf(s + bias[co], 0.f);
    }
}

// ---------------------------------------------------------------------------
// 4-tensor fp32 -> f16 cast into CONTIGUOUS dest (w2h_s|w3h_s|w2h_i|w3h_i).
// ---------------------------------------------------------------------------
__global__ __launch_bounds__(256) void cast4(
    const float* __restrict__ s0, const float* __restrict__ s1,
    const float* __restrict__ s2, const float* __restrict__ s3,
    _Float16* __restrict__ dst)
{
    const int N0 = 294912, N1 = 524288, N2 = 294912, N3 = 524288;
    const int T = N0 + N1 + N2 + N3;
    for (int i = blockIdx.x * 256 + threadIdx.x; i < T; i += gridDim.x * 256) {
        float x;
        if (i < N0)                x = s0[i];
        else if (i < N0 + N1)      x = s1[i - N0];
        else if (i < N0 + N1 + N2) x = s2[i - N0 - N1];
        else                       x = s3[i - N0 - N1 - N2];
        dst[i] = (_Float16)x;
    }
}

// ---------------------------------------------------------------------------
// w1 cast with K-pad 75 -> 96 (both branches in one dispatch, grid.y picks).
// ---------------------------------------------------------------------------
__global__ __launch_bounds__(256) void cast_w1_pad(
    const float* __restrict__ s0, _Float16* __restrict__ d0,
    const float* __restrict__ s1, _Float16* __restrict__ d1)
{
    const float* s = blockIdx.y ? s1 : s0;
    _Float16* d = blockIdx.y ? d1 : d0;
    int i = blockIdx.x * 256 + threadIdx.x;
    if (i < 128 * 96) {
        int co = i / 96, k = i % 96;
        d[i] = (k < 75) ? (_Float16)s[co * 75 + k] : (_Float16)0.f;
    }
}

// ---------------------------------------------------------------------------
// FC split-K: partial dot -> atomicAdd into out[b*NO+o] (pre-zeroed).
// ---------------------------------------------------------------------------
__global__ __launch_bounds__(256) void fc_atomic(
    const float* __restrict__ z, const float* __restrict__ fcw,
    float* __restrict__ out, int Kdim, int NO, int KSPL)
{
    const int b = blockIdx.x, o = blockIdx.y, ks = blockIdx.z;
    const int kchunk = Kdim / KSPL;
    const int k0 = ks * kchunk;
    const float* zp = z + (size_t)b * Kdim + k0;
    const float* wp = fcw + (size_t)o * Kdim + k0;
    float s = 0.f;
    for (int k = threadIdx.x; k < kchunk; k += 256) s = fmaf(zp[k], wp[k], s);
    __shared__ float red[4];
    for (int off = 32; off; off >>= 1) s += __shfl_down(s, off, 64);
    if ((threadIdx.x & 63) == 0) red[threadIdx.x >> 6] = s;
    __syncthreads();
    if (threadIdx.x == 0)
        atomicAdd(&out[(size_t)b * NO + o], red[0] + red[1] + red[2] + red[3]);
}

// ---------------------------------------------------------------------------
// m = reshape(|h|,3,3)^T; n = max L1 row norm + 1e-4; msc = m / n.
// ---------------------------------------------------------------------------
__global__ void build_m(const float* __restrict__ h, float* __restrict__ msc)
{
    int b = threadIdx.x;
    if (b < 16) {
        float m[9];
#pragma unroll
        for (int i = 0; i < 3; ++i)
#pragma unroll
            for (int j = 0; j < 3; ++j) m[i * 3 + j] = fabsf(h[b * 9 + j * 3 + i]);
        float n = 0.f;
#pragma unroll
        for (int i = 0; i < 3; ++i) {
            float r = m[i * 3] + m[i * 3 + 1] + m[i * 3 + 2];
            n = fmaxf(n, r);
        }
        n += 1e-4f;
        float inv = 1.f / n;
#pragma unroll
        for (int k = 0; k < 9; ++k) msc[b * 9 + k] = m[k] * inv;
    }
}

// ---------------------------------------------------------------------------
// est[b] = inv(msc[b]) @ |ill[b]|
// ---------------------------------------------------------------------------
__global__ void final_est(const float* __restrict__ msc, const float* __restrict__ ill,
                          float* __restrict__ out)
{
    int bidx = threadIdx.x;
    if (bidx < 16) {
        const float* m = msc + bidx * 9;
        float a = m[0], b = m[1], c = m[2];
        float d = m[3], e = m[4], f = m[5];
        float g = m[6], h = m[7], i = m[8];
        float A = e * i - f * h, B = f * g - d * i, C = d * h - e * g;
        float D = c * h - b * i, E = a * i - c * g, F = b * g - a * h;
        float G = b * f - c * e, H = c * d - a * f, I = a * e - b * d;
        float det = a * A + b * B + c * C;
        float inv_det = 1.f / det;
        float x0 = fabsf(ill[bidx * 3 + 0]);
        float x1 = fabsf(ill[bidx * 3 + 1]);
        float x2 = fabsf(ill[bidx * 3 + 2]);
        out[bidx * 3 + 0] = (A * x0 + D * x1 + G * x2) * inv_det;
        out[bidx * 3 + 1] = (B * x0 + E * x1 + H * x2) * inv_det;
        out[bidx * 3 + 2] = (C * x0 + F * x1 + I * x2) * inv_det;
    }
}

extern "C" void kernel_launch(void* const* d_in, const int* in_sizes, int n_in,
                              void* d_out, int out_size, void* d_ws, size_t ws_size,
                              hipStream_t stream)
{
    (void)in_sizes; (void)n_in; (void)out_size; (void)ws_size;
    const float* image = (const float*)d_in[0];
    const float* su_s  = (const float*)d_in[1];
    const float* sv_s  = (const float*)d_in[2];
    const float* c_s   = (const float*)d_in[3];
    const float* w1_s  = (const float*)d_in[4];
    const float* b1_s  = (const float*)d_in[5];
    const float* w2_s  = (const float*)d_in[6];
    const float* b2_s  = (const float*)d_in[7];
    const float* w3_s  = (const float*)d_in[8];
    const float* b3_s  = (const float*)d_in[9];
    const float* fc_s  = (const float*)d_in[10];
    const float* su_i  = (const float*)d_in[11];
    const float* sv_i  = (const float*)d_in[12];
    const float* c_i   = (const float*)d_in[13];
    const float* w1_i  = (const float*)d_in[14];
    const float* b1_i  = (const float*)d_in[15];
    const float* w2_i  = (const float*)d_in[16];
    const float* b2_i  = (const float*)d_in[17];
    const float* w3_i  = (const float*)d_in[18];
    const float* b3_i  = (const float*)d_in[19];
    const float* fc_i  = (const float*)d_in[20];

    // ---- workspace layout: cumulative pointer arithmetic ONLY ----
    float* W     = (float*)d_ws;
    float* hist  = W;                         // 16*3*61*61 = 178608 f
    float* o3    = hist + 178608;             // 16*512*169 = 1384448 f
    float* hd    = o3 + 1384448;              // 144 f
    float* hsum3 = hd + 144;                  // 48 f (memset together w/ hd)
    float* msc   = hsum3 + 48;                // 144 f (NOT re-zeroed)
    float* p2    = msc + 144;                 // 4*16*256*196 = 3211264 f
    float* p3    = p2 + 3211264;              // 4*16*512*169 = 5537792 f
    float* hpart = p3 + 5537792;              // 48*HSP*4096 = 4128768 f
    _Float16* o1h   = (_Float16*)(hpart + 48 * HSP * 4096);
    _Float16* o2h   = o1h   + 1722368;        // o1h: 16*128*841 halfs
    _Float16* w2h_s = o2h   + 802816;         // o2h: 16*256*196 halfs
    _Float16* w3h_s = w2h_s + 294912;         // w2h: 256*1152 halfs
    _Float16* w2h_i = w3h_s + 524288;         // w3h: 512*1024 halfs
    _Float16* w3h_i = w2h_i + 294912;
    _Float16* w1h_s = w3h_i + 524288;         // after w3h_i's FULL extent
    _Float16* w1h_i = w1h_s + 12288;          // w1h: 128*96 halfs
    // total ~66 MB

    const int FCK = 512 * 13 * 13;
    const int O2_TOT = 16 * 256 * 196;
    const int O3_TOT = 16 * 512 * 169;

    // ---- weight prep (f16 casts): dests w2h_s..w3h_i are contiguous ----
    cast_w1_pad<<<dim3(48, 2), 256, 0, stream>>>(w1_s, w1h_s, w1_i, w1h_i);
    cast4<<<1024, 256, 0, stream>>>(w2_s, w3_s, w2_i, w3_i, w2h_s);

    // ================= sensor branch =================
    hipMemsetAsync(hd, 0, 192 * 4, stream);   // hd(144) + hsum3(48)
    hist_mfma<<<dim3(48, HSP), 256, 0, stream>>>(image, su_s, sv_s, c_s, nullptr, hpart);
    reduce_hist<<<dim3(48, 4), 256, 0, stream>>>(hpart, hist, hsum3);
    conv1_mfma<<<dim3(16, 7), 256, 0, stream>>>(hist, hsum3, w1h_s, b1_s, o1h);
    conv_mfma<128, 256, 3, 2, 29, 14, 128, 4, 96><<<dim3(16, 2, 4), 256, 0, stream>>>(o1h, w2h_s, p2);
    reduce_bias_relu_f16<<<1024, 256, 0, stream>>>(p2, b2_s, o2h, 256, 196, O2_TOT, 4);
    conv_mfma<256, 512, 2, 1, 14, 13, 128, 4, 64><<<dim3(16, 4, 4), 256, 0, stream>>>(o2h, w3h_s, p3);
    reduce_bias_relu<<<1024, 256, 0, stream>>>(p3, b3_s, o3, 512, 169, O3_TOT, 4);
    fc_atomic<<<dim3(16, 9, 8), 256, 0, stream>>>(o3, fc_s, hd, FCK, 9, 8);
    build_m<<<1, 64, 0, stream>>>(hd, msc);

    // ================= illuminant branch =================
    hipMemsetAsync(hd, 0, 192 * 4, stream);   // hd + hsum3; msc preserved
    hist_mfma<<<dim3(48, HSP), 256, 0, stream>>>(image, su_i, sv_i, c_i, msc, hpart);
    reduce_hist<<<dim3(48, 4), 256, 0, stream>>>(hpart, hist, hsum3);
    conv1_mfma<<<dim3(16, 7), 256, 0, stream>>>(hist, hsum3, w1h_i, b1_i, o1h);
    conv_mfma<128, 256, 3, 2, 29, 14, 128, 4, 96><<<dim3(16, 2, 4), 256, 0, stream>>>(o1h, w2h_i, p2);
    reduce_bias_relu_f16<<<1024, 256, 0, stream>>>(p2, b2_i, o2h, 256, 196, O2_TOT, 4);
    conv_mfma<256, 512, 2, 1, 14, 13, 128, 4, 64><<<dim3(16, 4, 4), 256, 0, stream>>>(o2h, w3h_i, p3);
    reduce_bias_relu<<<1024, 256, 0, stream>>>(p3, b3_i, o3, 512, 169, O3_TOT, 4);
    fc_atomic<<<dim3(16, 3, 8), 256, 0, stream>>>(o3, fc_i, hd, FCK, 3, 8);
    final_est<<<1, 64, 0, stream>>>(msc, hd, (float*)d_out);
}

// Round 12
// 381.568 us; speedup vs baseline: 1.1905x; 1.0620x over previous
//
#include <hip/hip_runtime.h>

#define P_PIX 22500
#define HB 61
#define HSP 21           // pixel splits for hist (48*21=1008 blocks ~ 3.94/CU)
#define PPB 1152         // pixels per hist block (HSP*PPB=24192 >= P_PIX)
#define NCHK 9           // 128-px chunks per hist block

typedef float f32x4 __attribute__((ext_vector_type(4)));
typedef _Float16 f16x8 __attribute__((ext_vector_type(8)));

// ---------------------------------------------------------------------------
// MFMA RGB-uv soft histogram (fp16 fragments).  grid (48, HSP), block 256.
// Unchanged from r11 (verified 50.5 us).
// ---------------------------------------------------------------------------
__global__ __launch_bounds__(256) void hist_mfma(
    const float* __restrict__ img, const float* __restrict__ su,
    const float* __restrict__ sv, const float* __restrict__ cw,
    const float* __restrict__ msc, float* __restrict__ hpart)
{
    const int bc = blockIdx.x;
    const int b = bc / 3, c = bc % 3;
    const int split = blockIdx.y;
    const int tid  = threadIdx.x;
    const int wv   = tid >> 6;
    const int lane = tid & 63;
    const int quad = lane >> 4;
    const int mr   = lane & 15;

    __shared__ __align__(16) _Float16 A_lds[8192];
    __shared__ __align__(16) _Float16 B_lds[8192];
    __shared__ float suu[128], svv[128], sww[128];

    const float sig_u = su[c], sig_v = sv[c];
    const float inv_su2 = 1.f / (sig_u * sig_u);
    const float inv_sv2 = 1.f / (sig_v * sig_v);
    const float cwc = cw[c];
    const float ubin = -3.f + 0.1f * (float)lane;

    const bool hasM = (msc != nullptr);
    float m00=0,m01=0,m02=0,m10=0,m11=0,m12=0,m20=0,m21=0,m22=0;
    if (hasM) {
        const float* mp = msc + b * 9;
        m00=mp[0]; m01=mp[1]; m02=mp[2];
        m10=mp[3]; m11=mp[4]; m12=mp[5];
        m20=mp[6]; m21=mp[7]; m22=mp[8];
    }

    const int p0   = split * PPB;
    const int pend = min(p0 + PPB, P_PIX);

    f32x4 acc[4];
#pragma unroll
    for (int nt = 0; nt < 4; ++nt) acc[nt] = (f32x4){0.f, 0.f, 0.f, 0.f};

    for (int chunk = 0; chunk < NCHK; ++chunk) {
        __syncthreads();
        if (tid < 128) {
            int px = p0 + chunk * 128 + tid;
            float u = 0.f, v = 0.f, wgt = 0.f;
            if (px < pend) {
                const float* ip = img + (size_t)b * 3 * P_PIX + px;
                float r = ip[0], g = ip[P_PIX], bl = ip[2 * P_PIX];
                if (hasM) {
                    float r2 = m00 * r + m01 * g + m02 * bl;
                    float g2 = m10 * r + m11 * g + m12 * bl;
                    float b2 = m20 * r + m21 * g + m22 * bl;
                    r = r2; g = g2; bl = b2;
                }
                r  = fminf(fmaxf(r, 0.f), 1.f);
                g  = fminf(fmaxf(g, 0.f), 1.f);
                bl = fminf(fmaxf(bl, 0.f), 1.f);
                float Iy = sqrtf(r * r + g * g + bl * bl);
                float lr = __logf(r + 1e-6f);
                float lg = __logf(g + 1e-6f);
                float lb = __logf(bl + 1e-6f);
                if (c == 0)      { u = lr - lg; v = lr - lb; }
                else if (c == 1) { u = lg - lr; v = lg - lb; }
                else             { u = lb - lr; v = lb - lg; }
                wgt = Iy * cwc;
            }
            suu[tid] = u; svv[tid] = v; sww[tid] = wgt;
        }
        __syncthreads();
#pragma unroll
        for (int r = 0; r < 4; ++r) {
            int pg = wv + 4 * r;
            f32x4 u0 = *(const f32x4*)&suu[pg * 8];
            f32x4 u1 = *(const f32x4*)&suu[pg * 8 + 4];
            f32x4 w0 = *(const f32x4*)&sww[pg * 8];
            f32x4 w1 = *(const f32x4*)&sww[pg * 8 + 4];
            f32x4 v0 = *(const f32x4*)&svv[pg * 8];
            f32x4 v1 = *(const f32x4*)&svv[pg * 8 + 4];
            f16x8 av, bv;
#pragma unroll
            for (int j = 0; j < 4; ++j) {
                float du = u0[j] - ubin;
                av[j] = (_Float16)(__expf(-du * du * inv_su2) * w0[j]);
                float dv = v0[j] - ubin;
                bv[j] = (_Float16)__expf(-dv * dv * inv_sv2);
            }
#pragma unroll
            for (int j = 0; j < 4; ++j) {
                float du = u1[j] - ubin;
                av[4 + j] = (_Float16)(__expf(-du * du * inv_su2) * w1[j]);
                float dv = v1[j] - ubin;
                bv[4 + j] = (_Float16)__expf(-dv * dv * inv_sv2);
            }
            *(f16x8*)&A_lds[(pg * 64 + lane) * 8] = av;
            *(f16x8*)&B_lds[(pg * 64 + lane) * 8] = bv;
        }
        __syncthreads();
#pragma unroll
        for (int kk = 0; kk < 4; ++kk) {
            int pgq = kk * 4 + quad;
            f16x8 av = *(const f16x8*)&A_lds[(pgq * 64 + wv * 16 + mr) * 8];
#pragma unroll
            for (int nt = 0; nt < 4; ++nt) {
                f16x8 bvv = *(const f16x8*)&B_lds[(pgq * 64 + nt * 16 + mr) * 8];
                acc[nt] = __builtin_amdgcn_mfma_f32_16x16x32_f16(av, bvv, acc[nt], 0, 0, 0);
            }
        }
    }

    float* hp = hpart + ((size_t)bc * HSP + split) * 4096;
#pragma unroll
    for (int nt = 0; nt < 4; ++nt) {
        int v = nt * 16 + mr;
#pragma unroll
        for (int r = 0; r < 4; ++r) {
            int u = wv * 16 + quad * 4 + r;
            hp[u * 64 + v] = acc[nt][r];
        }
    }
}

// ---------------------------------------------------------------------------
// Sum HSP slabs -> hist[bc][61*61]; per-(b,c) total -> hsum3[bc].
// ---------------------------------------------------------------------------
__global__ __launch_bounds__(256) void reduce_hist(
    const float* __restrict__ hpart, float* __restrict__ hist,
    float* __restrict__ hsum3)
{
    const int bc = blockIdx.x;
    const int part = blockIdx.y;
    const int tid = threadIdx.x;
    const float* base = hpart + (size_t)bc * HSP * 4096;
    float lsum = 0.f;
#pragma unroll
    for (int t = 0; t < 4; ++t) {
        int idx = part * 1024 + t * 256 + tid;
        int u = idx >> 6, v = idx & 63;
        float s = 0.f;
        for (int sp = 0; sp < HSP; ++sp) s += base[sp * 4096 + idx];
        if (u < HB && v < HB) {
            hist[(size_t)bc * (HB * HB) + u * HB + v] = s;
            lsum += s;
        }
    }
    __shared__ float red[4];
    for (int off = 32; off; off >>= 1) lsum += __shfl_down(lsum, off, 64);
    if ((tid & 63) == 0) red[tid >> 6] = lsum;
    __syncthreads();
    if (tid == 0) atomicAdd(&hsum3[bc], red[0] + red[1] + red[2] + red[3]);
}

// ---------------------------------------------------------------------------
// conv1 implicit-GEMM MFMA, NHWC OUTPUT: o1h[b][sp(841)][co(128)].
// A=activations (hist gather, norm fused), B=weights -> D[row=sp][col=co];
// lanes write 16 consecutive co -> coalesced NHWC stores.
// ---------------------------------------------------------------------------
__global__ __launch_bounds__(256) void conv1_mfma(
    const float* __restrict__ hist,     // [B][3][3721] UNnormalized
    const float* __restrict__ hsum3,    // [48]
    const _Float16* __restrict__ w1h,   // [128][96] (zero-padded, CHW k-order)
    const float* __restrict__ bias,     // [128]
    _Float16* __restrict__ out)         // [B][841][128] NHWC
{
    const int b    = blockIdx.x;
    const int m0   = blockIdx.y * 128;
    const int tid  = threadIdx.x;
    const int wv   = tid >> 6;
    const int lane = tid & 63;
    const int quad = lane >> 4;
    const int mr   = lane & 15;

    __shared__ __align__(16) _Float16 A_lds[128 * 96];

    const float sc = 1.f / (hsum3[b * 3] + hsum3[b * 3 + 1] + hsum3[b * 3 + 2] + 1e-6f);
    const float* inb = hist + (size_t)b * 3 * 3721;

    for (int slot = tid; slot < 1536; slot += 256) {
        int m  = slot & 127;
        int kg = slot >> 7;
        int mg = m0 + m;
        bool mok = (mg < 841);
        int oh = mok ? mg / 29 : 0;
        int ow = mok ? mg % 29 : 0;
        const float* pbase = inb + (oh * 2) * 61 + (ow * 2);
        f16x8 av;
#pragma unroll
        for (int j = 0; j < 8; ++j) {
            int k = kg * 8 + j;
            float x = 0.f;
            if (mok && k < 75) {
                int ci = k / 25, r = k % 25;
                int kh = r / 5, kw = r % 5;
                x = pbase[ci * 3721 + kh * 61 + kw] * sc;
            }
            av[j] = (_Float16)x;
        }
        *(f16x8*)&A_lds[(kg * 128 + m) * 8] = av;
    }
    __syncthreads();

    f16x8 wf[3][2];
#pragma unroll
    for (int ks = 0; ks < 3; ++ks)
#pragma unroll
        for (int nt = 0; nt < 2; ++nt) {
            int co = (wv * 2 + nt) * 16 + mr;
            wf[ks][nt] = *(const f16x8*)&w1h[co * 96 + ks * 32 + quad * 8];
        }

    f32x4 acc[8][2];
#pragma unroll
    for (int mt = 0; mt < 8; ++mt)
#pragma unroll
        for (int nt = 0; nt < 2; ++nt) acc[mt][nt] = (f32x4){0.f, 0.f, 0.f, 0.f};

#pragma unroll
    for (int ks = 0; ks < 3; ++ks)
#pragma unroll
        for (int mt = 0; mt < 8; ++mt) {
            f16x8 bv = *(const f16x8*)&A_lds[((ks * 4 + quad) * 128 + mt * 16 + mr) * 8];
#pragma unroll
            for (int nt = 0; nt < 2; ++nt)
                acc[mt][nt] = __builtin_amdgcn_mfma_f32_16x16x32_f16(bv, wf[ks][nt], acc[mt][nt], 0, 0, 0);
        }

    // D[row = sp local = quad*4+r][col = co = mr]; NHWC store
#pragma unroll
    for (int mt = 0; mt < 8; ++mt) {
#pragma unroll
        for (int r = 0; r < 4; ++r) {
            int sp = m0 + mt * 16 + quad * 4 + r;
            if (sp >= 841) continue;
#pragma unroll
            for (int nt = 0; nt < 2; ++nt) {
                int co = (wv * 2 + nt) * 16 + mr;
                float y = acc[mt][nt][r] + bias[co];
                out[((size_t)b * 841 + sp) * 128 + co] = (_Float16)fmaxf(y, 0.f);
            }
        }
    }
}

// ---------------------------------------------------------------------------
// conv2/conv3 implicit-GEMM MFMA, NHWC in/out.
// in_h: [B][IN*IN][CIN], w_h: [COUT][KK][CIN] (k = khkw*CIN + ci -> 8
// consecutive k are 8 consecutive ci => ONE dwordx4 per staging slot).
// D[row=sp][col=co]; partials p[ks][b][OSZ][COUT] coalesced over co.
// ---------------------------------------------------------------------------
template<int CIN, int COUT, int Kk, int S, int IN, int OUT,
         int NPB, int KSPL, int KCH>
__global__ __launch_bounds__(256) void conv_mfma(
    const _Float16* __restrict__ in_h,
    const _Float16* __restrict__ w_h,
    float* __restrict__ out)             // [KSPL][B][OSZ][COUT]
{
    constexpr int KK   = Kk * Kk;
    constexpr int OSZ  = OUT * OUT;
    constexpr int MT   = (OSZ + 15) / 16;
    constexpr int MP   = MT * 16;
    constexpr int KTOT = CIN * KK;
    constexpr int KC   = KTOT / KSPL;
    constexpr int NCHUNK = KC / KCH;
    constexpr int NT   = NPB / 64;
    constexpr int KSN  = KCH / 32;
    constexpr int SLOTS = MP * (KCH / 8);

    const int b   = blockIdx.x;
    const int co0 = blockIdx.y * NPB;
    const int k00 = blockIdx.z * KC;
    const int tid  = threadIdx.x;
    const int wv   = tid >> 6;
    const int lane = tid & 63;
    const int quad = lane >> 4;
    const int mr   = lane & 15;

    __shared__ __align__(16) _Float16 A_lds[MP * KCH];

    const _Float16* inb = in_h + (size_t)b * (IN * IN) * CIN;
    float* outp = out + (size_t)blockIdx.z * gridDim.x * OSZ * COUT;

    f32x4 acc[MT][NT];
#pragma unroll
    for (int mt = 0; mt < MT; ++mt)
#pragma unroll
        for (int nt = 0; nt < NT; ++nt) acc[mt][nt] = (f32x4){0.f, 0.f, 0.f, 0.f};

    for (int ch = 0; ch < NCHUNK; ++ch) {
        const int k0 = k00 + ch * KCH;
        __syncthreads();
        for (int slot = tid; slot < SLOTS; slot += 256) {
            int m  = slot % MP;
            int kg = slot / MP;
            bool mok = (m < OSZ);
            int oh = mok ? m / OUT : 0;
            int ow = mok ? m % OUT : 0;
            int kbase = k0 + kg * 8;
            int khkw = kbase / CIN;      // CIN pow2 -> shift
            int ci0  = kbase % CIN;
            int kh = khkw / Kk, kw = khkw % Kk;
            f16x8 av = (f16x8)(_Float16)0.f;
            if (mok)
                av = *(const f16x8*)&inb[((size_t)((oh * S + kh) * IN + (ow * S + kw))) * CIN + ci0];
            *(f16x8*)&A_lds[(kg * MP + m) * 8] = av;
        }
        __syncthreads();
        f16x8 wf[KSN][NT];
#pragma unroll
        for (int ks = 0; ks < KSN; ++ks)
#pragma unroll
            for (int nt = 0; nt < NT; ++nt) {
                int co = co0 + (wv * NT + nt) * 16 + mr;
                wf[ks][nt] = *(const f16x8*)&w_h[(size_t)co * KTOT + k0 + ks * 32 + quad * 8];
            }
#pragma unroll
        for (int ks = 0; ks < KSN; ++ks) {
#pragma unroll
            for (int mt = 0; mt < MT; ++mt) {
                f16x8 bv = *(const f16x8*)&A_lds[((ks * 4 + quad) * MP + mt * 16 + mr) * 8];
#pragma unroll
                for (int nt = 0; nt < NT; ++nt)
                    acc[mt][nt] = __builtin_amdgcn_mfma_f32_16x16x32_f16(bv, wf[ks][nt], acc[mt][nt], 0, 0, 0);
            }
        }
    }

    // D[row = sp local][col = co]; NHWC partial store
#pragma unroll
    for (int mt = 0; mt < MT; ++mt) {
#pragma unroll
        for (int r = 0; r < 4; ++r) {
            int sp = mt * 16 + quad * 4 + r;
            if (sp >= OSZ) continue;
#pragma unroll
            for (int nt = 0; nt < NT; ++nt) {
                int co = co0 + (wv * NT + nt) * 16 + mr;
                outp[((size_t)b * OSZ + sp) * COUT + co] = acc[mt][nt][r];
            }
        }
    }
}

// ---------------------------------------------------------------------------
// sum KSPL split-K partials + bias + ReLU (NHWC: co = i % cout) -> f16.
// ---------------------------------------------------------------------------
__global__ __launch_bounds__(256) void reduce_bias_relu_f16(
    const float* __restrict__ p, const float* __restrict__ bias,
    _Float16* __restrict__ out, int cout, int total, int kspl)
{
    for (int i = blockIdx.x * 256 + threadIdx.x; i < total; i += gridDim.x * 256) {
        float s = 0.f;
        for (int ks = 0; ks < kspl; ++ks) s += p[(size_t)ks * total + i];
        out[i] = (_Float16)fmaxf(s + bias[i % cout], 0.f);
    }
}

__global__ __launch_bounds__(256) void reduce_bias_relu(
    const float* __restrict__ p, const float* __restrict__ bias,
    float* __restrict__ out, int cout, int total, int kspl)
{
    for (int i = blockIdx.x * 256 + threadIdx.x; i < total; i += gridDim.x * 256) {
        float s = 0.f;
        for (int ks = 0; ks < kspl; ++ks) s += p[(size_t)ks * total + i];
        out[i] = fmaxf(s + bias[i % cout], 0.f);
    }
}

// ---------------------------------------------------------------------------
// w2/w3 f16 cast with [co][ci][khkw] -> [co][khkw][ci] transpose, 4 tensors
// into contiguous dest w2h_s|w3h_s|w2h_i|w3h_i.
// ---------------------------------------------------------------------------
__global__ __launch_bounds__(256) void cast_w23(
    const float* __restrict__ w2s, const float* __restrict__ w3s,
    const float* __restrict__ w2i, const float* __restrict__ w3i,
    _Float16* __restrict__ dst)
{
    const int N2 = 294912, N3 = 524288;   // 256*1152, 512*1024
    const int T = 2 * (N2 + N3);
    for (int i = blockIdx.x * 256 + threadIdx.x; i < T; i += gridDim.x * 256) {
        int j = i;
        const float* s;
        int CK, KKn;
        if (j < N2)                { s = w2s; CK = 1152; KKn = 9; }
        else if (j < N2 + N3)      { s = w3s; j -= N2; CK = 1024; KKn = 4; }
        else if (j < N2 + N3 + N2) { s = w2i; j -= N2 + N3; CK = 1152; KKn = 9; }
        else                       { s = w3i; j -= 2 * N2 + N3; CK = 1024; KKn = 4; }
        int co = j / CK, rem = j % CK;
        int ci = rem % (CK / KKn), khkw = rem / (CK / KKn);
        dst[i] = (_Float16)s[co * CK + ci * KKn + khkw];
    }
}

// ---------------------------------------------------------------------------
// fc weight transpose [o][co*169+sp] -> [o][sp*512+co], fp32, 9+3 rows.
// ---------------------------------------------------------------------------
__global__ __launch_bounds__(256) void cast_fc(
    const float* __restrict__ fs, const float* __restrict__ fi,
    float* __restrict__ dst)
{
    const int K = 86528;                  // 512*169
    const int T = 12 * K;
    for (int i = blockIdx.x * 256 + threadIdx.x; i < T; i += gridDim.x * 256) {
        int o = i / K, rem = i % K;
        int sp = rem / 512, co = rem % 512;
        const float* s = (o < 9) ? (fs + o * K) : (fi + (o - 9) * K);
        dst[i] = s[co * 169 + sp];
    }
}

// ---------------------------------------------------------------------------
// w1 cast with K-pad 75 -> 96 (CHW k-order kept; conv1 staging is CHW).
// ---------------------------------------------------------------------------
__global__ __launch_bounds__(256) void cast_w1_pad(
    const float* __restrict__ s0, _Float16* __restrict__ d0,
    const float* __restrict__ s1, _Float16* __restrict__ d1)
{
    const float* s = blockIdx.y ? s1 : s0;
    _Float16* d = blockIdx.y ? d1 : d0;
    int i = blockIdx.x * 256 + threadIdx.x;
    if (i < 128 * 96) {
        int co = i / 96, k = i % 96;
        d[i] = (k < 75) ? (_Float16)s[co * 75 + k] : (_Float16)0.f;
    }
}

// ---------------------------------------------------------------------------
// FC split-K (z NHWC-flat, fcw_t pre-transposed to match).
// ---------------------------------------------------------------------------
__global__ __launch_bounds__(256) void fc_atomic(
    const float* __restrict__ z, const float* __restrict__ fcw,
    float* __restrict__ out, int Kdim, int NO, int KSPL)
{
    const int b = blockIdx.x, o = blockIdx.y, ks = blockIdx.z;
    const int kchunk = Kdim / KSPL;
    const int k0 = ks * kchunk;
    const float* zp = z + (size_t)b * Kdim + k0;
    const float* wp = fcw + (size_t)o * Kdim + k0;
    float s = 0.f;
    for (int k = threadIdx.x; k < kchunk; k += 256) s = fmaf(zp[k], wp[k], s);
    __shared__ float red[4];
    for (int off = 32; off; off >>= 1) s += __shfl_down(s, off, 64);
    if ((threadIdx.x & 63) == 0) red[threadIdx.x >> 6] = s;
    __syncthreads();
    if (threadIdx.x == 0)
        atomicAdd(&out[(size_t)b * NO + o], red[0] + red[1] + red[2] + red[3]);
}

// ---------------------------------------------------------------------------
// m = reshape(|h|,3,3)^T; n = max L1 row norm + 1e-4; msc = m / n.
// ---------------------------------------------------------------------------
__global__ void build_m(const float* __restrict__ h, float* __restrict__ msc)
{
    int b = threadIdx.x;
    if (b < 16) {
        float m[9];
#pragma unroll
        for (int i = 0; i < 3; ++i)
#pragma unroll
            for (int j = 0; j < 3; ++j) m[i * 3 + j] = fabsf(h[b * 9 + j * 3 + i]);
        float n = 0.f;
#pragma unroll
        for (int i = 0; i < 3; ++i) {
            float r = m[i * 3] + m[i * 3 + 1] + m[i * 3 + 2];
            n = fmaxf(n, r);
        }
        n += 1e-4f;
        float inv = 1.f / n;
#pragma unroll
        for (int k = 0; k < 9; ++k) msc[b * 9 + k] = m[k] * inv;
    }
}

// ---------------------------------------------------------------------------
// est[b] = inv(msc[b]) @ |ill[b]|
// ---------------------------------------------------------------------------
__global__ void final_est(const float* __restrict__ msc, const float* __restrict__ ill,
                          float* __restrict__ out)
{
    int bidx = threadIdx.x;
    if (bidx < 16) {
        const float* m = msc + bidx * 9;
        float a = m[0], b = m[1], c = m[2];
        float d = m[3], e = m[4], f = m[5];
        float g = m[6], h = m[7], i = m[8];
        float A = e * i - f * h, B = f * g - d * i, C = d * h - e * g;
        float D = c * h - b * i, E = a * i - c * g, F = b * g - a * h;
        float G = b * f - c * e, H = c * d - a * f, I = a * e - b * d;
        float det = a * A + b * B + c * C;
        float inv_det = 1.f / det;
        float x0 = fabsf(ill[bidx * 3 + 0]);
        float x1 = fabsf(ill[bidx * 3 + 1]);
        float x2 = fabsf(ill[bidx * 3 + 2]);
        out[bidx * 3 + 0] = (A * x0 + D * x1 + G * x2) * inv_det;
        out[bidx * 3 + 1] = (B * x0 + E * x1 + H * x2) * inv_det;
        out[bidx * 3 + 2] = (C * x0 + F * x1 + I * x2) * inv_det;
    }
}

extern "C" void kernel_launch(void* const* d_in, const int* in_sizes, int n_in,
                              void* d_out, int out_size, void* d_ws, size_t ws_size,
                              hipStream_t stream)
{
    (void)in_sizes; (void)n_in; (void)out_size; (void)ws_size;
    const float* image = (const float*)d_in[0];
    const float* su_s  = (const float*)d_in[1];
    const float* sv_s  = (const float*)d_in[2];
    const float* c_s   = (const float*)d_in[3];
    const float* w1_s  = (const float*)d_in[4];
    const float* b1_s  = (const float*)d_in[5];
    const float* w2_s  = (const float*)d_in[6];
    const float* b2_s  = (const float*)d_in[7];
    const float* w3_s  = (const float*)d_in[8];
    const float* b3_s  = (const float*)d_in[9];
    const float* fc_s  = (const float*)d_in[10];
    const float* su_i  = (const float*)d_in[11];
    const float* sv_i  = (const float*)d_in[12];
    const float* c_i   = (const float*)d_in[13];
    const float* w1_i  = (const float*)d_in[14];
    const float* b1_i  = (const float*)d_in[15];
    const float* w2_i  = (const float*)d_in[16];
    const float* b2_i  = (const float*)d_in[17];
    const float* w3_i  = (const float*)d_in[18];
    const float* b3_i  = (const float*)d_in[19];
    const float* fc_i  = (const float*)d_in[20];

    // ---- workspace: cumulative pointer arithmetic ONLY ----
    float* W     = (float*)d_ws;
    float* hist  = W;                         // 178608 f
    float* o3    = hist + 178608;             // 16*169*512 = 1384448 f (NHWC)
    float* hd    = o3 + 1384448;              // 144 f
    float* hsum3 = hd + 144;                  // 48 f
    float* msc   = hsum3 + 48;                // 144 f
    float* fct   = msc + 144;                 // 12*86528 = 1038336 f
    float* p2    = fct + 1038336;             // 4*16*196*256 = 3211264 f
    float* p3    = p2 + 3211264;              // 4*16*169*512 = 5537792 f
    float* hpart = p3 + 5537792;              // 48*HSP*4096 = 4128768 f
    _Float16* o1h   = (_Float16*)(hpart + 48 * HSP * 4096);
    _Float16* o2h   = o1h   + 1722368;        // 16*841*128 halfs (NHWC)
    _Float16* w2h_s = o2h   + 802816;         // 16*196*256 halfs (NHWC)
    _Float16* w3h_s = w2h_s + 294912;
    _Float16* w2h_i = w3h_s + 524288;
    _Float16* w3h_i = w2h_i + 294912;
    _Float16* w1h_s = w3h_i + 524288;
    _Float16* w1h_i = w1h_s + 12288;
    // total ~70 MB

    const int FCK = 512 * 13 * 13;
    const int O2_TOT = 16 * 196 * 256;
    const int O3_TOT = 16 * 169 * 512;
    float* fct_s = fct;
    float* fct_i = fct + 9 * FCK;

    // ---- weight prep ----
    cast_w1_pad<<<dim3(48, 2), 256, 0, stream>>>(w1_s, w1h_s, w1_i, w1h_i);
    cast_w23<<<1024, 256, 0, stream>>>(w2_s, w3_s, w2_i, w3_i, w2h_s);
    cast_fc<<<1024, 256, 0, stream>>>(fc_s, fc_i, fct);

    // ================= sensor branch =================
    hipMemsetAsync(hd, 0, 192 * 4, stream);
    hist_mfma<<<dim3(48, HSP), 256, 0, stream>>>(image, su_s, sv_s, c_s, nullptr, hpart);
    reduce_hist<<<dim3(48, 4), 256, 0, stream>>>(hpart, hist, hsum3);
    conv1_mfma<<<dim3(16, 7), 256, 0, stream>>>(hist, hsum3, w1h_s, b1_s, o1h);
    conv_mfma<128, 256, 3, 2, 29, 14, 128, 4, 96><<<dim3(16, 2, 4), 256, 0, stream>>>(o1h, w2h_s, p2);
    reduce_bias_relu_f16<<<1024, 256, 0, stream>>>(p2, b2_s, o2h, 256, O2_TOT, 4);
    conv_mfma<256, 512, 2, 1, 14, 13, 128, 4, 64><<<dim3(16, 4, 4), 256, 0, stream>>>(o2h, w3h_s, p3);
    reduce_bias_relu<<<1024, 256, 0, stream>>>(p3, b3_s, o3, 512, O3_TOT, 4);
    fc_atomic<<<dim3(16, 9, 8), 256, 0, stream>>>(o3, fct_s, hd, FCK, 9, 8);
    build_m<<<1, 64, 0, stream>>>(hd, msc);

    // ================= illuminant branch =================
    hipMemsetAsync(hd, 0, 192 * 4, stream);
    hist_mfma<<<dim3(48, HSP), 256, 0, stream>>>(image, su_i, sv_i, c_i, msc, hpart);
    reduce_hist<<<dim3(48, 4), 256, 0, stream>>>(hpart, hist, hsum3);
    conv1_mfma<<<dim3(16, 7), 256, 0, stream>>>(hist, hsum3, w1h_i, b1_i, o1h);
    conv_mfma<128, 256, 3, 2, 29, 14, 128, 4, 96><<<dim3(16, 2, 4), 256, 0, stream>>>(o1h, w2h_i, p2);
    reduce_bias_relu_f16<<<1024, 256, 0, stream>>>(p2, b2_i, o2h, 256, O2_TOT, 4);
    conv_mfma<256, 512, 2, 1, 14, 13, 128, 4, 64><<<dim3(16, 4, 4), 256, 0, stream>>>(o2h, w3h_i, p3);
    reduce_bias_relu<<<1024, 256, 0, stream>>>(p3, b3_i, o3, 512, O3_TOT, 4);
    fc_atomic<<<dim3(16, 3, 8), 256, 0, stream>>>(o3, fct_i, hd, FCK, 3, 8);
    final_est<<<1, 64, 0, stream>>>(msc, hd, (float*)d_out);
}

// Round 13
// 376.141 us; speedup vs baseline: 1.2076x; 1.0144x over previous
//
#include <hip/hip_runtime.h>

#define P_PIX 22500
#define HB 61
#define HSP 28           // pixel splits for hist (48*28=1344 blocks ~ 5.25/CU)
#define PPB 832          // pixels per hist block (28*832=23296 >= 22500)
#define NCHK 7           // 128-px chunks per hist block

typedef float f32x4 __attribute__((ext_vector_type(4)));
typedef _Float16 f16x8 __attribute__((ext_vector_type(8)));
typedef _Float16 f16x4 __attribute__((ext_vector_type(4)));

// ---------------------------------------------------------------------------
// MFMA RGB-uv soft histogram.  grid (48, HSP), block 256.
// A fragments (ku*w) are computed DIRECTLY INTO REGISTERS by the consuming
// lane (bin = 16wv+mr, pixels = 8*(4kk+quad)+j); only the B table (kv, all
// 64 bins needed by every wave) goes through LDS.  Factored Gaussian (r7),
// __expf (r10), no atomics (r11).
// ---------------------------------------------------------------------------
__global__ __launch_bounds__(256) void hist_mfma(
    const float* __restrict__ img, const float* __restrict__ su,
    const float* __restrict__ sv, const float* __restrict__ cw,
    const float* __restrict__ msc, float* __restrict__ hpart)
{
    const int bc = blockIdx.x;
    const int b = bc / 3, c = bc % 3;
    const int split = blockIdx.y;
    const int tid  = threadIdx.x;
    const int wv   = tid >> 6;
    const int lane = tid & 63;
    const int quad = lane >> 4;
    const int mr   = lane & 15;

    __shared__ __align__(16) _Float16 B_lds[8192];   // [pg(16)][vbin(64)][j(8)]
    __shared__ float suu[128], svv[128], sww[128];

    const float sig_u = su[c], sig_v = sv[c];
    const float inv_su2 = 1.f / (sig_u * sig_u);
    const float inv_sv2 = 1.f / (sig_v * sig_v);
    const float cwc = cw[c];
    const float ubin_b = -3.f + 0.1f * (float)lane;            // B: bin = lane
    const float ubin_a = -3.f + 0.1f * (float)(wv * 16 + mr);  // A: own row

    const bool hasM = (msc != nullptr);
    float m00=0,m01=0,m02=0,m10=0,m11=0,m12=0,m20=0,m21=0,m22=0;
    if (hasM) {
        const float* mp = msc + b * 9;
        m00=mp[0]; m01=mp[1]; m02=mp[2];
        m10=mp[3]; m11=mp[4]; m12=mp[5];
        m20=mp[6]; m21=mp[7]; m22=mp[8];
    }

    const int p0   = split * PPB;
    const int pend = min(p0 + PPB, P_PIX);

    f32x4 acc[4];
#pragma unroll
    for (int nt = 0; nt < 4; ++nt) acc[nt] = (f32x4){0.f, 0.f, 0.f, 0.f};

    for (int chunk = 0; chunk < NCHK; ++chunk) {
        __syncthreads();
        // ---- phase 1: (u, v, weight) for 128 pixels ----
        if (tid < 128) {
            int px = p0 + chunk * 128 + tid;
            float u = 0.f, v = 0.f, wgt = 0.f;
            if (px < pend) {
                const float* ip = img + (size_t)b * 3 * P_PIX + px;
                float r = ip[0], g = ip[P_PIX], bl = ip[2 * P_PIX];
                if (hasM) {
                    float r2 = m00 * r + m01 * g + m02 * bl;
                    float g2 = m10 * r + m11 * g + m12 * bl;
                    float b2 = m20 * r + m21 * g + m22 * bl;
                    r = r2; g = g2; bl = b2;
                }
                r  = fminf(fmaxf(r, 0.f), 1.f);
                g  = fminf(fmaxf(g, 0.f), 1.f);
                bl = fminf(fmaxf(bl, 0.f), 1.f);
                float Iy = sqrtf(r * r + g * g + bl * bl);
                float lr = __logf(r + 1e-6f);
                float lg = __logf(g + 1e-6f);
                float lb = __logf(bl + 1e-6f);
                if (c == 0)      { u = lr - lg; v = lr - lb; }
                else if (c == 1) { u = lg - lr; v = lg - lb; }
                else             { u = lb - lr; v = lb - lg; }
                wgt = Iy * cwc;
            }
            suu[tid] = u; svv[tid] = v; sww[tid] = wgt;
        }
        __syncthreads();
        // ---- phase 2a: B table (kv) into LDS ----
#pragma unroll
        for (int r = 0; r < 4; ++r) {
            int pg = wv + 4 * r;
            f32x4 v0 = *(const f32x4*)&svv[pg * 8];
            f32x4 v1 = *(const f32x4*)&svv[pg * 8 + 4];
            f16x8 bv;
#pragma unroll
            for (int j = 0; j < 4; ++j) {
                float dv = v0[j] - ubin_b;
                bv[j] = (_Float16)__expf(-dv * dv * inv_sv2);
                float dv1 = v1[j] - ubin_b;
                bv[4 + j] = (_Float16)__expf(-dv1 * dv1 * inv_sv2);
            }
            *(f16x8*)&B_lds[(pg * 64 + lane) * 8] = bv;
        }
        // ---- phase 2b: A fragments (ku*w) into registers ----
        f16x8 af[4];
#pragma unroll
        for (int kk = 0; kk < 4; ++kk) {
            int pxg = kk * 4 + quad;           // quad-uniform -> LDS broadcast
            f32x4 u0 = *(const f32x4*)&suu[pxg * 8];
            f32x4 u1 = *(const f32x4*)&suu[pxg * 8 + 4];
            f32x4 w0 = *(const f32x4*)&sww[pxg * 8];
            f32x4 w1 = *(const f32x4*)&sww[pxg * 8 + 4];
#pragma unroll
            for (int j = 0; j < 4; ++j) {
                float du = u0[j] - ubin_a;
                af[kk][j] = (_Float16)(__expf(-du * du * inv_su2) * w0[j]);
                float du1 = u1[j] - ubin_a;
                af[kk][4 + j] = (_Float16)(__expf(-du1 * du1 * inv_su2) * w1[j]);
            }
        }
        __syncthreads();
        // ---- phase 3: MFMA ----
#pragma unroll
        for (int kk = 0; kk < 4; ++kk) {
            int pgq = kk * 4 + quad;
#pragma unroll
            for (int nt = 0; nt < 4; ++nt) {
                f16x8 bvv = *(const f16x8*)&B_lds[(pgq * 64 + nt * 16 + mr) * 8];
                acc[nt] = __builtin_amdgcn_mfma_f32_16x16x32_f16(af[kk], bvv, acc[nt], 0, 0, 0);
            }
        }
    }

    float* hp = hpart + ((size_t)bc * HSP + split) * 4096;
#pragma unroll
    for (int nt = 0; nt < 4; ++nt) {
        int v = nt * 16 + mr;
#pragma unroll
        for (int r = 0; r < 4; ++r) {
            int u = wv * 16 + quad * 4 + r;
            hp[u * 64 + v] = acc[nt][r];
        }
    }
}

// ---------------------------------------------------------------------------
// Sum HSP slabs -> hist[bc][61*61]; per-(b,c) total -> hsum3[bc].
// ---------------------------------------------------------------------------
__global__ __launch_bounds__(256) void reduce_hist(
    const float* __restrict__ hpart, float* __restrict__ hist,
    float* __restrict__ hsum3)
{
    const int bc = blockIdx.x;
    const int part = blockIdx.y;
    const int tid = threadIdx.x;
    const float* base = hpart + (size_t)bc * HSP * 4096;
    float lsum = 0.f;
#pragma unroll
    for (int t = 0; t < 4; ++t) {
        int idx = part * 1024 + t * 256 + tid;
        int u = idx >> 6, v = idx & 63;
        float s = 0.f;
        for (int sp = 0; sp < HSP; ++sp) s += base[sp * 4096 + idx];
        if (u < HB && v < HB) {
            hist[(size_t)bc * (HB * HB) + u * HB + v] = s;
            lsum += s;
        }
    }
    __shared__ float red[4];
    for (int off = 32; off; off >>= 1) lsum += __shfl_down(lsum, off, 64);
    if ((tid & 63) == 0) red[tid >> 6] = lsum;
    __syncthreads();
    if (tid == 0) atomicAdd(&hsum3[bc], red[0] + red[1] + red[2] + red[3]);
}

// ---------------------------------------------------------------------------
// conv1 implicit-GEMM MFMA, NHWC output (r12, verified).
// ---------------------------------------------------------------------------
__global__ __launch_bounds__(256) void conv1_mfma(
    const float* __restrict__ hist, const float* __restrict__ hsum3,
    const _Float16* __restrict__ w1h, const float* __restrict__ bias,
    _Float16* __restrict__ out)
{
    const int b    = blockIdx.x;
    const int m0   = blockIdx.y * 128;
    const int tid  = threadIdx.x;
    const int wv   = tid >> 6;
    const int lane = tid & 63;
    const int quad = lane >> 4;
    const int mr   = lane & 15;

    __shared__ __align__(16) _Float16 A_lds[128 * 96];

    const float sc = 1.f / (hsum3[b * 3] + hsum3[b * 3 + 1] + hsum3[b * 3 + 2] + 1e-6f);
    const float* inb = hist + (size_t)b * 3 * 3721;

    for (int slot = tid; slot < 1536; slot += 256) {
        int m  = slot & 127;
        int kg = slot >> 7;
        int mg = m0 + m;
        bool mok = (mg < 841);
        int oh = mok ? mg / 29 : 0;
        int ow = mok ? mg % 29 : 0;
        const float* pbase = inb + (oh * 2) * 61 + (ow * 2);
        f16x8 av;
#pragma unroll
        for (int j = 0; j < 8; ++j) {
            int k = kg * 8 + j;
            float x = 0.f;
            if (mok && k < 75) {
                int ci = k / 25, r = k % 25;
                int kh = r / 5, kw = r % 5;
                x = pbase[ci * 3721 + kh * 61 + kw] * sc;
            }
            av[j] = (_Float16)x;
        }
        *(f16x8*)&A_lds[(kg * 128 + m) * 8] = av;
    }
    __syncthreads();

    f16x8 wf[3][2];
#pragma unroll
    for (int ks = 0; ks < 3; ++ks)
#pragma unroll
        for (int nt = 0; nt < 2; ++nt) {
            int co = (wv * 2 + nt) * 16 + mr;
            wf[ks][nt] = *(const f16x8*)&w1h[co * 96 + ks * 32 + quad * 8];
        }

    f32x4 acc[8][2];
#pragma unroll
    for (int mt = 0; mt < 8; ++mt)
#pragma unroll
        for (int nt = 0; nt < 2; ++nt) acc[mt][nt] = (f32x4){0.f, 0.f, 0.f, 0.f};

#pragma unroll
    for (int ks = 0; ks < 3; ++ks)
#pragma unroll
        for (int mt = 0; mt < 8; ++mt) {
            f16x8 bv = *(const f16x8*)&A_lds[((ks * 4 + quad) * 128 + mt * 16 + mr) * 8];
#pragma unroll
            for (int nt = 0; nt < 2; ++nt)
                acc[mt][nt] = __builtin_amdgcn_mfma_f32_16x16x32_f16(bv, wf[ks][nt], acc[mt][nt], 0, 0, 0);
        }

#pragma unroll
    for (int mt = 0; mt < 8; ++mt) {
#pragma unroll
        for (int r = 0; r < 4; ++r) {
            int sp = m0 + mt * 16 + quad * 4 + r;
            if (sp >= 841) continue;
#pragma unroll
            for (int nt = 0; nt < 2; ++nt) {
                int co = (wv * 2 + nt) * 16 + mr;
                float y = acc[mt][nt][r] + bias[co];
                out[((size_t)b * 841 + sp) * 128 + co] = (_Float16)fmaxf(y, 0.f);
            }
        }
    }
}

// ---------------------------------------------------------------------------
// conv2/conv3 implicit-GEMM MFMA, NHWC in/out (r12, verified).
// ---------------------------------------------------------------------------
template<int CIN, int COUT, int Kk, int S, int IN, int OUT,
         int NPB, int KSPL, int KCH>
__global__ __launch_bounds__(256) void conv_mfma(
    const _Float16* __restrict__ in_h,
    const _Float16* __restrict__ w_h,
    float* __restrict__ out)             // [KSPL][B][OSZ][COUT]
{
    constexpr int KK   = Kk * Kk;
    constexpr int OSZ  = OUT * OUT;
    constexpr int MT   = (OSZ + 15) / 16;
    constexpr int MP   = MT * 16;
    constexpr int KTOT = CIN * KK;
    constexpr int KC   = KTOT / KSPL;
    constexpr int NCHUNK = KC / KCH;
    constexpr int NT   = NPB / 64;
    constexpr int KSN  = KCH / 32;
    constexpr int SLOTS = MP * (KCH / 8);

    const int b   = blockIdx.x;
    const int co0 = blockIdx.y * NPB;
    const int k00 = blockIdx.z * KC;
    const int tid  = threadIdx.x;
    const int wv   = tid >> 6;
    const int lane = tid & 63;
    const int quad = lane >> 4;
    const int mr   = lane & 15;

    __shared__ __align__(16) _Float16 A_lds[MP * KCH];

    const _Float16* inb = in_h + (size_t)b * (IN * IN) * CIN;
    float* outp = out + (size_t)blockIdx.z * gridDim.x * OSZ * COUT;

    f32x4 acc[MT][NT];
#pragma unroll
    for (int mt = 0; mt < MT; ++mt)
#pragma unroll
        for (int nt = 0; nt < NT; ++nt) acc[mt][nt] = (f32x4){0.f, 0.f, 0.f, 0.f};

    for (int ch = 0; ch < NCHUNK; ++ch) {
        const int k0 = k00 + ch * KCH;
        __syncthreads();
        for (int slot = tid; slot < SLOTS; slot += 256) {
            int m  = slot % MP;
            int kg = slot / MP;
            bool mok = (m < OSZ);
            int oh = mok ? m / OUT : 0;
            int ow = mok ? m % OUT : 0;
            int kbase = k0 + kg * 8;
            int khkw = kbase / CIN;
            int ci0  = kbase % CIN;
            int kh = khkw / Kk, kw = khkw % Kk;
            f16x8 av = (f16x8)(_Float16)0.f;
            if (mok)
                av = *(const f16x8*)&inb[((size_t)((oh * S + kh) * IN + (ow * S + kw))) * CIN + ci0];
            *(f16x8*)&A_lds[(kg * MP + m) * 8] = av;
        }
        __syncthreads();
        f16x8 wf[KSN][NT];
#pragma unroll
        for (int ks = 0; ks < KSN; ++ks)
#pragma unroll
            for (int nt = 0; nt < NT; ++nt) {
                int co = co0 + (wv * NT + nt) * 16 + mr;
                wf[ks][nt] = *(const f16x8*)&w_h[(size_t)co * KTOT + k0 + ks * 32 + quad * 8];
            }
#pragma unroll
        for (int ks = 0; ks < KSN; ++ks) {
#pragma unroll
            for (int mt = 0; mt < MT; ++mt) {
                f16x8 bv = *(const f16x8*)&A_lds[((ks * 4 + quad) * MP + mt * 16 + mr) * 8];
#pragma unroll
                for (int nt = 0; nt < NT; ++nt)
                    acc[mt][nt] = __builtin_amdgcn_mfma_f32_16x16x32_f16(bv, wf[ks][nt], acc[mt][nt], 0, 0, 0);
            }
        }
    }

#pragma unroll
    for (int mt = 0; mt < MT; ++mt) {
#pragma unroll
        for (int r = 0; r < 4; ++r) {
            int sp = mt * 16 + quad * 4 + r;
            if (sp >= OSZ) continue;
#pragma unroll
            for (int nt = 0; nt < NT; ++nt) {
                int co = co0 + (wv * NT + nt) * 16 + mr;
                outp[((size_t)b * OSZ + sp) * COUT + co] = acc[mt][nt][r];
            }
        }
    }
}

// ---------------------------------------------------------------------------
// float4 split-K reduce + bias + ReLU -> f16 (NHWC: co = 4i % cout).
// ---------------------------------------------------------------------------
__global__ __launch_bounds__(256) void reduce_bias_relu_f16(
    const float* __restrict__ p, const float* __restrict__ bias,
    _Float16* __restrict__ out, int cout, int total4, int kspl, int total)
{
    for (int i4 = blockIdx.x * 256 + threadIdx.x; i4 < total4; i4 += gridDim.x * 256) {
        f32x4 s = (f32x4){0.f, 0.f, 0.f, 0.f};
        for (int ks = 0; ks < kspl; ++ks)
            s += *(const f32x4*)&p[(size_t)ks * total + i4 * 4];
        f32x4 bb = *(const f32x4*)&bias[(i4 * 4) % cout];
        f16x4 o;
#pragma unroll
        for (int j = 0; j < 4; ++j) o[j] = (_Float16)fmaxf(s[j] + bb[j], 0.f);
        *(f16x4*)&out[(size_t)i4 * 4] = o;
    }
}

__global__ __launch_bounds__(256) void reduce_bias_relu(
    const float* __restrict__ p, const float* __restrict__ bias,
    float* __restrict__ out, int cout, int total4, int kspl, int total)
{
    for (int i4 = blockIdx.x * 256 + threadIdx.x; i4 < total4; i4 += gridDim.x * 256) {
        f32x4 s = (f32x4){0.f, 0.f, 0.f, 0.f};
        for (int ks = 0; ks < kspl; ++ks)
            s += *(const f32x4*)&p[(size_t)ks * total + i4 * 4];
        f32x4 bb = *(const f32x4*)&bias[(i4 * 4) % cout];
        f32x4 o;
#pragma unroll
        for (int j = 0; j < 4; ++j) o[j] = fmaxf(s[j] + bb[j], 0.f);
        *(f32x4*)&out[(size_t)i4 * 4] = o;
    }
}

// ---------------------------------------------------------------------------
// ONE weight-prep kernel: w1 pad (both), w2/w3 NHWC transpose (4 tensors),
// fc transpose (12 rows).  Grid-stride over all ranges.
// ---------------------------------------------------------------------------
__global__ __launch_bounds__(256) void prep_weights(
    const float* __restrict__ w1s, const float* __restrict__ w1i,
    const float* __restrict__ w2s, const float* __restrict__ w3s,
    const float* __restrict__ w2i, const float* __restrict__ w3i,
    const float* __restrict__ fcs, const float* __restrict__ fci,
    _Float16* __restrict__ w1h, _Float16* __restrict__ w23,
    float* __restrict__ fct)
{
    const int R1 = 24576;               // 2 * 128*96
    const int N2 = 294912, N3 = 524288;
    const int R2 = 2 * (N2 + N3);
    const int K = 86528;
    const int R3 = 12 * K;
    const int T = R1 + R2 + R3;
    for (int i = blockIdx.x * 256 + threadIdx.x; i < T; i += gridDim.x * 256) {
        if (i < R1) {
            int br = i / 12288, r = i % 12288;
            int co = r / 96, k = r % 96;
            const float* s = br ? w1i : w1s;
            w1h[i] = (k < 75) ? (_Float16)s[co * 75 + k] : (_Float16)0.f;
        } else if (i < R1 + R2) {
            int j = i - R1;
            int out_idx = j;
            const float* s; int CK, KKn;
            if (j < N2)                { s = w2s; CK = 1152; KKn = 9; }
            else if (j < N2 + N3)      { s = w3s; j -= N2; CK = 1024; KKn = 4; }
            else if (j < 2 * N2 + N3)  { s = w2i; j -= N2 + N3; CK = 1152; KKn = 9; }
            else                       { s = w3i; j -= 2 * N2 + N3; CK = 1024; KKn = 4; }
            int co = j / CK, rem = j % CK;
            int ci = rem % (CK / KKn), khkw = rem / (CK / KKn);
            w23[out_idx] = (_Float16)s[co * CK + ci * KKn + khkw];
        } else {
            int j = i - R1 - R2;
            int o = j / K, rem = j % K;
            int sp = rem / 512, co = rem % 512;
            const float* s = (o < 9) ? (fcs + o * K) : (fci + (o - 9) * K);
            fct[j] = s[co * 169 + sp];
        }
    }
}

// ---------------------------------------------------------------------------
// FC split-K, float4 loads (z NHWC-flat, fcw_t pre-transposed).
// ---------------------------------------------------------------------------
__global__ __launch_bounds__(256) void fc_atomic(
    const float* __restrict__ z, const float* __restrict__ fcw,
    float* __restrict__ out, int Kdim, int NO, int KSPL)
{
    const int b = blockIdx.x, o = blockIdx.y, ks = blockIdx.z;
    const int kchunk = Kdim / KSPL;
    const int k0 = ks * kchunk;
    const f32x4* zp = (const f32x4*)(z + (size_t)b * Kdim + k0);
    const f32x4* wp = (const f32x4*)(fcw + (size_t)o * Kdim + k0);
    const int n4 = kchunk / 4;
    f32x4 s4 = (f32x4){0.f, 0.f, 0.f, 0.f};
    for (int k = threadIdx.x; k < n4; k += 256) {
        f32x4 a = zp[k], w = wp[k];
        s4 += a * w;
    }
    float s = s4[0] + s4[1] + s4[2] + s4[3];
    __shared__ float red[4];
    for (int off = 32; off; off >>= 1) s += __shfl_down(s, off, 64);
    if ((threadIdx.x & 63) == 0) red[threadIdx.x >> 6] = s;
    __syncthreads();
    if (threadIdx.x == 0)
        atomicAdd(&out[(size_t)b * NO + o], red[0] + red[1] + red[2] + red[3]);
}

// ---------------------------------------------------------------------------
// m = reshape(|h|,3,3)^T; n = max L1 row norm + 1e-4; msc = m / n.
// ---------------------------------------------------------------------------
__global__ void build_m(const float* __restrict__ h, float* __restrict__ msc)
{
    int b = threadIdx.x;
    if (b < 16) {
        float m[9];
#pragma unroll
        for (int i = 0; i < 3; ++i)
#pragma unroll
            for (int j = 0; j < 3; ++j) m[i * 3 + j] = fabsf(h[b * 9 + j * 3 + i]);
        float n = 0.f;
#pragma unroll
        for (int i = 0; i < 3; ++i) {
            float r = m[i * 3] + m[i * 3 + 1] + m[i * 3 + 2];
            n = fmaxf(n, r);
        }
        n += 1e-4f;
        float inv = 1.f / n;
#pragma unroll
        for (int k = 0; k < 9; ++k) msc[b * 9 + k] = m[k] * inv;
    }
}

// ---------------------------------------------------------------------------
// est[b] = inv(msc[b]) @ |ill[b]|
// ---------------------------------------------------------------------------
__global__ void final_est(const float* __restrict__ msc, const float* __restrict__ ill,
                          float* __restrict__ out)
{
    int bidx = threadIdx.x;
    if (bidx < 16) {
        const float* m = msc + bidx * 9;
        float a = m[0], b = m[1], c = m[2];
        float d = m[3], e = m[4], f = m[5];
        float g = m[6], h = m[7], i = m[8];
        float A = e * i - f * h, B = f * g - d * i, C = d * h - e * g;
        float D = c * h - b * i, E = a * i - c * g, F = b * g - a * h;
        float G = b * f - c * e, H = c * d - a * f, I = a * e - b * d;
        float det = a * A + b * B + c * C;
        float inv_det = 1.f / det;
        float x0 = fabsf(ill[bidx * 3 + 0]);
        float x1 = fabsf(ill[bidx * 3 + 1]);
        float x2 = fabsf(ill[bidx * 3 + 2]);
        out[bidx * 3 + 0] = (A * x0 + D * x1 + G * x2) * inv_det;
        out[bidx * 3 + 1] = (B * x0 + E * x1 + H * x2) * inv_det;
        out[bidx * 3 + 2] = (C * x0 + F * x1 + I * x2) * inv_det;
    }
}

extern "C" void kernel_launch(void* const* d_in, const int* in_sizes, int n_in,
                              void* d_out, int out_size, void* d_ws, size_t ws_size,
                              hipStream_t stream)
{
    (void)in_sizes; (void)n_in; (void)out_size; (void)ws_size;
    const float* image = (const float*)d_in[0];
    const float* su_s  = (const float*)d_in[1];
    const float* sv_s  = (const float*)d_in[2];
    const float* c_s   = (const float*)d_in[3];
    const float* w1_s  = (const float*)d_in[4];
    const float* b1_s  = (const float*)d_in[5];
    const float* w2_s  = (const float*)d_in[6];
    const float* b2_s  = (const float*)d_in[7];
    const float* w3_s  = (const float*)d_in[8];
    const float* b3_s  = (const float*)d_in[9];
    const float* fc_s  = (const float*)d_in[10];
    const float* su_i  = (const float*)d_in[11];
    const float* sv_i  = (const float*)d_in[12];
    const float* c_i   = (const float*)d_in[13];
    const float* w1_i  = (const float*)d_in[14];
    const float* b1_i  = (const float*)d_in[15];
    const float* w2_i  = (const float*)d_in[16];
    const float* b2_i  = (const float*)d_in[17];
    const float* w3_i  = (const float*)d_in[18];
    const float* b3_i  = (const float*)d_in[19];
    const float* fc_i  = (const float*)d_in[20];

    // ---- workspace: cumulative pointer arithmetic ONLY ----
    float* W     = (float*)d_ws;
    float* hist  = W;                         // 178608 f
    float* o3    = hist + 178608;             // 16*169*512 = 1384448 f (NHWC)
    float* hd    = o3 + 1384448;              // 144 f
    float* hsum3 = hd + 144;                  // 48 f
    float* msc   = hsum3 + 48;                // 144 f
    float* fct   = msc + 144;                 // 12*86528 = 1038336 f
    float* p2    = fct + 1038336;             // 4*16*196*256 = 3211264 f
    float* p3    = p2 + 3211264;              // 2*16*169*512 = 2768896 f
    float* hpart = p3 + 2768896;              // 48*HSP*4096 = 5505024 f
    _Float16* o1h   = (_Float16*)(hpart + 48 * HSP * 4096);
    _Float16* o2h   = o1h   + 1722368;        // 16*841*128 halfs
    _Float16* w2h_s = o2h   + 802816;         // 16*196*256 halfs
    _Float16* w3h_s = w2h_s + 294912;
    _Float16* w2h_i = w3h_s + 524288;
    _Float16* w3h_i = w2h_i + 294912;
    _Float16* w1h_s = w3h_i + 524288;
    _Float16* w1h_i = w1h_s + 12288;

    const int FCK = 512 * 13 * 13;
    const int O2_TOT = 16 * 196 * 256;
    const int O3_TOT = 16 * 169 * 512;
    float* fct_s = fct;
    float* fct_i = fct + 9 * FCK;

    // ---- single weight-prep dispatch ----
    prep_weights<<<1024, 256, 0, stream>>>(w1_s, w1_i, w2_s, w3_s, w2_i, w3_i,
                                           fc_s, fc_i, w1h_s, w2h_s, fct);

    // ================= sensor branch =================
    hipMemsetAsync(hd, 0, 192 * 4, stream);
    hist_mfma<<<dim3(48, HSP), 256, 0, stream>>>(image, su_s, sv_s, c_s, nullptr, hpart);
    reduce_hist<<<dim3(48, 4), 256, 0, stream>>>(hpart, hist, hsum3);
    conv1_mfma<<<dim3(16, 7), 256, 0, stream>>>(hist, hsum3, w1h_s, b1_s, o1h);
    conv_mfma<128, 256, 3, 2, 29, 14, 128, 4, 96><<<dim3(16, 2, 4), 256, 0, stream>>>(o1h, w2h_s, p2);
    reduce_bias_relu_f16<<<784, 256, 0, stream>>>(p2, b2_s, o2h, 256, O2_TOT / 4, 4, O2_TOT);
    conv_mfma<256, 512, 2, 1, 14, 13, 128, 2, 64><<<dim3(16, 4, 2), 256, 0, stream>>>(o2h, w3h_s, p3);
    reduce_bias_relu<<<1024, 256, 0, stream>>>(p3, b3_s, o3, 512, O3_TOT / 4, 2, O3_TOT);
    fc_atomic<<<dim3(16, 9, 8), 256, 0, stream>>>(o3, fct_s, hd, FCK, 9, 8);
    build_m<<<1, 64, 0, stream>>>(hd, msc);

    // ================= illuminant branch =================
    hipMemsetAsync(hd, 0, 192 * 4, stream);
    hist_mfma<<<dim3(48, HSP), 256, 0, stream>>>(image, su_i, sv_i, c_i, msc, hpart);
    reduce_hist<<<dim3(48, 4), 256, 0, stream>>>(hpart, hist, hsum3);
    conv1_mfma<<<dim3(16, 7), 256, 0, stream>>>(hist, hsum3, w1h_i, b1_i, o1h);
    conv_mfma<128, 256, 3, 2, 29, 14, 128, 4, 96><<<dim3(16, 2, 4), 256, 0, stream>>>(o1h, w2h_i, p2);
    reduce_bias_relu_f16<<<784, 256, 0, stream>>>(p2, b2_i, o2h, 256, O2_TOT / 4, 4, O2_TOT);
    conv_mfma<256, 512, 2, 1, 14, 13, 128, 2, 64><<<dim3(16, 4, 2), 256, 0, stream>>>(o2h, w3h_i, p3);
    reduce_bias_relu<<<1024, 256, 0, stream>>>(p3, b3_i, o3, 512, O3_TOT / 4, 2, O3_TOT);
    fc_atomic<<<dim3(16, 3, 8), 256, 0, stream>>>(o3, fct_i, hd, FCK, 3, 8);
    final_est<<<1, 64, 0, stream>>>(msc, hd, (float*)d_out);
}

// Round 14
// 358.665 us; speedup vs baseline: 1.2665x; 1.0487x over previous
//
#include <hip/hip_runtime.h>

#define P_PIX 22500
#define HB 61
#define HSP 21           // pixel splits for hist (r12 measured optimum)
#define PPB 1152
#define NCHK 9

typedef float f32x4 __attribute__((ext_vector_type(4)));
typedef _Float16 f16x8 __attribute__((ext_vector_type(8)));
typedef _Float16 f16x4 __attribute__((ext_vector_type(4)));

// ---------------------------------------------------------------------------
// MFMA RGB-uv soft histogram.  grid (48, HSP), block 256.
// Register-resident A fragments (bin = 16wv+mr); B table in LDS.
// Factored Gaussian (r7), __expf (r10), no atomics (r11), HSP=21 (r12/r13).
// ---------------------------------------------------------------------------
__global__ __launch_bounds__(256) void hist_mfma(
    const float* __restrict__ img, const float* __restrict__ su,
    const float* __restrict__ sv, const float* __restrict__ cw,
    const float* __restrict__ msc, float* __restrict__ hpart)
{
    const int bc = blockIdx.x;
    const int b = bc / 3, c = bc % 3;
    const int split = blockIdx.y;
    const int tid  = threadIdx.x;
    const int wv   = tid >> 6;
    const int lane = tid & 63;
    const int quad = lane >> 4;
    const int mr   = lane & 15;

    __shared__ __align__(16) _Float16 B_lds[8192];
    __shared__ float suu[128], svv[128], sww[128];

    const float sig_u = su[c], sig_v = sv[c];
    const float inv_su2 = 1.f / (sig_u * sig_u);
    const float inv_sv2 = 1.f / (sig_v * sig_v);
    const float cwc = cw[c];
    const float ubin_b = -3.f + 0.1f * (float)lane;
    const float ubin_a = -3.f + 0.1f * (float)(wv * 16 + mr);

    const bool hasM = (msc != nullptr);
    float m00=0,m01=0,m02=0,m10=0,m11=0,m12=0,m20=0,m21=0,m22=0;
    if (hasM) {
        const float* mp = msc + b * 9;
        m00=mp[0]; m01=mp[1]; m02=mp[2];
        m10=mp[3]; m11=mp[4]; m12=mp[5];
        m20=mp[6]; m21=mp[7]; m22=mp[8];
    }

    const int p0   = split * PPB;
    const int pend = min(p0 + PPB, P_PIX);

    f32x4 acc[4];
#pragma unroll
    for (int nt = 0; nt < 4; ++nt) acc[nt] = (f32x4){0.f, 0.f, 0.f, 0.f};

    for (int chunk = 0; chunk < NCHK; ++chunk) {
        __syncthreads();
        if (tid < 128) {
            int px = p0 + chunk * 128 + tid;
            float u = 0.f, v = 0.f, wgt = 0.f;
            if (px < pend) {
                const float* ip = img + (size_t)b * 3 * P_PIX + px;
                float r = ip[0], g = ip[P_PIX], bl = ip[2 * P_PIX];
                if (hasM) {
                    float r2 = m00 * r + m01 * g + m02 * bl;
                    float g2 = m10 * r + m11 * g + m12 * bl;
                    float b2 = m20 * r + m21 * g + m22 * bl;
                    r = r2; g = g2; bl = b2;
                }
                r  = fminf(fmaxf(r, 0.f), 1.f);
                g  = fminf(fmaxf(g, 0.f), 1.f);
                bl = fminf(fmaxf(bl, 0.f), 1.f);
                float Iy = sqrtf(r * r + g * g + bl * bl);
                float lr = __logf(r + 1e-6f);
                float lg = __logf(g + 1e-6f);
                float lb = __logf(bl + 1e-6f);
                if (c == 0)      { u = lr - lg; v = lr - lb; }
                else if (c == 1) { u = lg - lr; v = lg - lb; }
                else             { u = lb - lr; v = lb - lg; }
                wgt = Iy * cwc;
            }
            suu[tid] = u; svv[tid] = v; sww[tid] = wgt;
        }
        __syncthreads();
        // B table (kv) into LDS
#pragma unroll
        for (int r = 0; r < 4; ++r) {
            int pg = wv + 4 * r;
            f32x4 v0 = *(const f32x4*)&svv[pg * 8];
            f32x4 v1 = *(const f32x4*)&svv[pg * 8 + 4];
            f16x8 bv;
#pragma unroll
            for (int j = 0; j < 4; ++j) {
                float dv = v0[j] - ubin_b;
                bv[j] = (_Float16)__expf(-dv * dv * inv_sv2);
                float dv1 = v1[j] - ubin_b;
                bv[4 + j] = (_Float16)__expf(-dv1 * dv1 * inv_sv2);
            }
            *(f16x8*)&B_lds[(pg * 64 + lane) * 8] = bv;
        }
        // A fragments (ku*w) into registers
        f16x8 af[4];
#pragma unroll
        for (int kk = 0; kk < 4; ++kk) {
            int pxg = kk * 4 + quad;
            f32x4 u0 = *(const f32x4*)&suu[pxg * 8];
            f32x4 u1 = *(const f32x4*)&suu[pxg * 8 + 4];
            f32x4 w0 = *(const f32x4*)&sww[pxg * 8];
            f32x4 w1 = *(const f32x4*)&sww[pxg * 8 + 4];
#pragma unroll
            for (int j = 0; j < 4; ++j) {
                float du = u0[j] - ubin_a;
                af[kk][j] = (_Float16)(__expf(-du * du * inv_su2) * w0[j]);
                float du1 = u1[j] - ubin_a;
                af[kk][4 + j] = (_Float16)(__expf(-du1 * du1 * inv_su2) * w1[j]);
            }
        }
        __syncthreads();
#pragma unroll
        for (int kk = 0; kk < 4; ++kk) {
            int pgq = kk * 4 + quad;
#pragma unroll
            for (int nt = 0; nt < 4; ++nt) {
                f16x8 bvv = *(const f16x8*)&B_lds[(pgq * 64 + nt * 16 + mr) * 8];
                acc[nt] = __builtin_amdgcn_mfma_f32_16x16x32_f16(af[kk], bvv, acc[nt], 0, 0, 0);
            }
        }
    }

    float* hp = hpart + ((size_t)bc * HSP + split) * 4096;
#pragma unroll
    for (int nt = 0; nt < 4; ++nt) {
        int v = nt * 16 + mr;
#pragma unroll
        for (int r = 0; r < 4; ++r) {
            int u = wv * 16 + quad * 4 + r;
            hp[u * 64 + v] = acc[nt][r];
        }
    }
}

// ---------------------------------------------------------------------------
// Sum HSP slabs -> hist; per-(b,c) total -> hsum3.
// ---------------------------------------------------------------------------
__global__ __launch_bounds__(256) void reduce_hist(
    const float* __restrict__ hpart, float* __restrict__ hist,
    float* __restrict__ hsum3)
{
    const int bc = blockIdx.x;
    const int part = blockIdx.y;
    const int tid = threadIdx.x;
    const float* base = hpart + (size_t)bc * HSP * 4096;
    float lsum = 0.f;
#pragma unroll
    for (int t = 0; t < 4; ++t) {
        int idx = part * 1024 + t * 256 + tid;
        int u = idx >> 6, v = idx & 63;
        float s = 0.f;
        for (int sp = 0; sp < HSP; ++sp) s += base[sp * 4096 + idx];
        if (u < HB && v < HB) {
            hist[(size_t)bc * (HB * HB) + u * HB + v] = s;
            lsum += s;
        }
    }
    __shared__ float red[4];
    for (int off = 32; off; off >>= 1) lsum += __shfl_down(lsum, off, 64);
    if ((tid & 63) == 0) red[tid >> 6] = lsum;
    __syncthreads();
    if (tid == 0) atomicAdd(&hsum3[bc], red[0] + red[1] + red[2] + red[3]);
}

// ---------------------------------------------------------------------------
// conv1 implicit-GEMM MFMA, NHWC output (r12, verified).
// ---------------------------------------------------------------------------
__global__ __launch_bounds__(256) void conv1_mfma(
    const float* __restrict__ hist, const float* __restrict__ hsum3,
    const _Float16* __restrict__ w1h, const float* __restrict__ bias,
    _Float16* __restrict__ out)
{
    const int b    = blockIdx.x;
    const int m0   = blockIdx.y * 128;
    const int tid  = threadIdx.x;
    const int wv   = tid >> 6;
    const int lane = tid & 63;
    const int quad = lane >> 4;
    const int mr   = lane & 15;

    __shared__ __align__(16) _Float16 A_lds[128 * 96];

    const float sc = 1.f / (hsum3[b * 3] + hsum3[b * 3 + 1] + hsum3[b * 3 + 2] + 1e-6f);
    const float* inb = hist + (size_t)b * 3 * 3721;

    for (int slot = tid; slot < 1536; slot += 256) {
        int m  = slot & 127;
        int kg = slot >> 7;
        int mg = m0 + m;
        bool mok = (mg < 841);
        int oh = mok ? mg / 29 : 0;
        int ow = mok ? mg % 29 : 0;
        const float* pbase = inb + (oh * 2) * 61 + (ow * 2);
        f16x8 av;
#pragma unroll
        for (int j = 0; j < 8; ++j) {
            int k = kg * 8 + j;
            float x = 0.f;
            if (mok && k < 75) {
                int ci = k / 25, r = k % 25;
                int kh = r / 5, kw = r % 5;
                x = pbase[ci * 3721 + kh * 61 + kw] * sc;
            }
            av[j] = (_Float16)x;
        }
        *(f16x8*)&A_lds[(kg * 128 + m) * 8] = av;
    }
    __syncthreads();

    f16x8 wf[3][2];
#pragma unroll
    for (int ks = 0; ks < 3; ++ks)
#pragma unroll
        for (int nt = 0; nt < 2; ++nt) {
            int co = (wv * 2 + nt) * 16 + mr;
            wf[ks][nt] = *(const f16x8*)&w1h[co * 96 + ks * 32 + quad * 8];
        }

    f32x4 acc[8][2];
#pragma unroll
    for (int mt = 0; mt < 8; ++mt)
#pragma unroll
        for (int nt = 0; nt < 2; ++nt) acc[mt][nt] = (f32x4){0.f, 0.f, 0.f, 0.f};

#pragma unroll
    for (int ks = 0; ks < 3; ++ks)
#pragma unroll
        for (int mt = 0; mt < 8; ++mt) {
            f16x8 bv = *(const f16x8*)&A_lds[((ks * 4 + quad) * 128 + mt * 16 + mr) * 8];
#pragma unroll
            for (int nt = 0; nt < 2; ++nt)
                acc[mt][nt] = __builtin_amdgcn_mfma_f32_16x16x32_f16(bv, wf[ks][nt], acc[mt][nt], 0, 0, 0);
        }

#pragma unroll
    for (int mt = 0; mt < 8; ++mt) {
#pragma unroll
        for (int r = 0; r < 4; ++r) {
            int sp = m0 + mt * 16 + quad * 4 + r;
            if (sp >= 841) continue;
#pragma unroll
            for (int nt = 0; nt < 2; ++nt) {
                int co = (wv * 2 + nt) * 16 + mr;
                float y = acc[mt][nt][r] + bias[co];
                out[((size_t)b * 841 + sp) * 128 + co] = (_Float16)fmaxf(y, 0.f);
            }
        }
    }
}

// ---------------------------------------------------------------------------
// conv2/conv3 implicit-GEMM MFMA, NHWC in/out (r12, verified).
// ---------------------------------------------------------------------------
template<int CIN, int COUT, int Kk, int S, int IN, int OUT,
         int NPB, int KSPL, int KCH>
__global__ __launch_bounds__(256) void conv_mfma(
    const _Float16* __restrict__ in_h,
    const _Float16* __restrict__ w_h,
    float* __restrict__ out)             // [KSPL][B][OSZ][COUT]
{
    constexpr int KK   = Kk * Kk;
    constexpr int OSZ  = OUT * OUT;
    constexpr int MT   = (OSZ + 15) / 16;
    constexpr int MP   = MT * 16;
    constexpr int KTOT = CIN * KK;
    constexpr int KC   = KTOT / KSPL;
    constexpr int NCHUNK = KC / KCH;
    constexpr int NT   = NPB / 64;
    constexpr int KSN  = KCH / 32;
    constexpr int SLOTS = MP * (KCH / 8);

    const int b   = blockIdx.x;
    const int co0 = blockIdx.y * NPB;
    const int k00 = blockIdx.z * KC;
    const int tid  = threadIdx.x;
    const int wv   = tid >> 6;
    const int lane = tid & 63;
    const int quad = lane >> 4;
    const int mr   = lane & 15;

    __shared__ __align__(16) _Float16 A_lds[MP * KCH];

    const _Float16* inb = in_h + (size_t)b * (IN * IN) * CIN;
    float* outp = out + (size_t)blockIdx.z * gridDim.x * OSZ * COUT;

    f32x4 acc[MT][NT];
#pragma unroll
    for (int mt = 0; mt < MT; ++mt)
#pragma unroll
        for (int nt = 0; nt < NT; ++nt) acc[mt][nt] = (f32x4){0.f, 0.f, 0.f, 0.f};

    for (int ch = 0; ch < NCHUNK; ++ch) {
        const int k0 = k00 + ch * KCH;
        __syncthreads();
        for (int slot = tid; slot < SLOTS; slot += 256) {
            int m  = slot % MP;
            int kg = slot / MP;
            bool mok = (m < OSZ);
            int oh = mok ? m / OUT : 0;
            int ow = mok ? m % OUT : 0;
            int kbase = k0 + kg * 8;
            int khkw = kbase / CIN;
            int ci0  = kbase % CIN;
            int kh = khkw / Kk, kw = khkw % Kk;
            f16x8 av = (f16x8)(_Float16)0.f;
            if (mok)
                av = *(const f16x8*)&inb[((size_t)((oh * S + kh) * IN + (ow * S + kw))) * CIN + ci0];
            *(f16x8*)&A_lds[(kg * MP + m) * 8] = av;
        }
        __syncthreads();
        f16x8 wf[KSN][NT];
#pragma unroll
        for (int ks = 0; ks < KSN; ++ks)
#pragma unroll
            for (int nt = 0; nt < NT; ++nt) {
                int co = co0 + (wv * NT + nt) * 16 + mr;
                wf[ks][nt] = *(const f16x8*)&w_h[(size_t)co * KTOT + k0 + ks * 32 + quad * 8];
            }
#pragma unroll
        for (int ks = 0; ks < KSN; ++ks) {
#pragma unroll
            for (int mt = 0; mt < MT; ++mt) {
                f16x8 bv = *(const f16x8*)&A_lds[((ks * 4 + quad) * MP + mt * 16 + mr) * 8];
#pragma unroll
                for (int nt = 0; nt < NT; ++nt)
                    acc[mt][nt] = __builtin_amdgcn_mfma_f32_16x16x32_f16(bv, wf[ks][nt], acc[mt][nt], 0, 0, 0);
            }
        }
    }

#pragma unroll
    for (int mt = 0; mt < MT; ++mt) {
#pragma unroll
        for (int r = 0; r < 4; ++r) {
            int sp = mt * 16 + quad * 4 + r;
            if (sp >= OSZ) continue;
#pragma unroll
            for (int nt = 0; nt < NT; ++nt) {
                int co = co0 + (wv * NT + nt) * 16 + mr;
                outp[((size_t)b * OSZ + sp) * COUT + co] = acc[mt][nt][r];
            }
        }
    }
}

// ---------------------------------------------------------------------------
// float4 split-K reduce + bias + ReLU -> f16 (NHWC: co = 4i % cout).
// ---------------------------------------------------------------------------
__global__ __launch_bounds__(256) void reduce_bias_relu_f16(
    const float* __restrict__ p, const float* __restrict__ bias,
    _Float16* __restrict__ out, int cout, int total4, int kspl, int total)
{
    for (int i4 = blockIdx.x * 256 + threadIdx.x; i4 < total4; i4 += gridDim.x * 256) {
        f32x4 s = (f32x4){0.f, 0.f, 0.f, 0.f};
        for (int ks = 0; ks < kspl; ++ks)
            s += *(const f32x4*)&p[(size_t)ks * total + i4 * 4];
        f32x4 bb = *(const f32x4*)&bias[(i4 * 4) % cout];
        f16x4 o;
#pragma unroll
        for (int j = 0; j < 4; ++j) o[j] = (_Float16)fmaxf(s[j] + bb[j], 0.f);
        *(f16x4*)&out[(size_t)i4 * 4] = o;
    }
}

// ---------------------------------------------------------------------------
// fc as split-K MFMA: M=16 (batch), N=16 (pad of NO), K=86528.
// grid 169, block 256 (4 waves x 128 k each); A=z[b][k] f16 direct from
// global, B=fch[o][k] (pre-transposed f16); LDS cross-wave reduce; 144
// guarded atomics per block into hd (pre-zeroed).
// ---------------------------------------------------------------------------
__global__ __launch_bounds__(256) void fc_mfma(
    const _Float16* __restrict__ z,     // [16][86528] NHWC-flat
    const _Float16* __restrict__ fcw,   // [NO][86528] transposed
    float* __restrict__ out, int NO)
{
    const int tid  = threadIdx.x;
    const int wv   = tid >> 6;
    const int lane = tid & 63;
    const int quad = lane >> 4;
    const int mr   = lane & 15;
    const int kw0  = blockIdx.x * 512 + wv * 128;

    __shared__ float sred[1024];

    f32x4 acc = (f32x4){0.f, 0.f, 0.f, 0.f};
    const bool bok = (mr < NO);
#pragma unroll
    for (int ks = 0; ks < 4; ++ks) {
        int kk = kw0 + ks * 32 + quad * 8;
        f16x8 av = *(const f16x8*)&z[(size_t)mr * 86528 + kk];
        f16x8 bw = (f16x8)(_Float16)0.f;
        if (bok) bw = *(const f16x8*)&fcw[(size_t)mr * 86528 + kk];
        acc = __builtin_amdgcn_mfma_f32_16x16x32_f16(av, bw, acc, 0, 0, 0);
    }
    // D[row=b=quad*4+r][col=o=mr] -> LDS
#pragma unroll
    for (int r = 0; r < 4; ++r)
        sred[wv * 256 + (quad * 4 + r) * 16 + mr] = acc[r];
    __syncthreads();
    if (tid < 256) {
        float s = sred[tid] + sred[256 + tid] + sred[512 + tid] + sred[768 + tid];
        int o = tid & 15, b = tid >> 4;
        if (o < NO) atomicAdd(&out[b * NO + o], s);
    }
}

// ---------------------------------------------------------------------------
// ONE weight-prep kernel: w1 pad, w2/w3 NHWC transpose, fc transpose -> f16.
// ---------------------------------------------------------------------------
__global__ __launch_bounds__(256) void prep_weights(
    const float* __restrict__ w1s, const float* __restrict__ w1i,
    const float* __restrict__ w2s, const float* __restrict__ w3s,
    const float* __restrict__ w2i, const float* __restrict__ w3i,
    const float* __restrict__ fcs, const float* __restrict__ fci,
    _Float16* __restrict__ w1h, _Float16* __restrict__ w23,
    _Float16* __restrict__ fch)
{
    const int R1 = 24576;
    const int N2 = 294912, N3 = 524288;
    const int R2 = 2 * (N2 + N3);
    const int K = 86528;
    const int R3 = 12 * K;
    const int T = R1 + R2 + R3;
    for (int i = blockIdx.x * 256 + threadIdx.x; i < T; i += gridDim.x * 256) {
        if (i < R1) {
            int br = i / 12288, r = i % 12288;
            int co = r / 96, k = r % 96;
            const float* s = br ? w1i : w1s;
            w1h[i] = (k < 75) ? (_Float16)s[co * 75 + k] : (_Float16)0.f;
        } else if (i < R1 + R2) {
            int j = i - R1;
            int out_idx = j;
            const float* s; int CK, KKn;
            if (j < N2)                { s = w2s; CK = 1152; KKn = 9; }
            else if (j < N2 + N3)      { s = w3s; j -= N2; CK = 1024; KKn = 4; }
            else if (j < 2 * N2 + N3)  { s = w2i; j -= N2 + N3; CK = 1152; KKn = 9; }
            else                       { s = w3i; j -= 2 * N2 + N3; CK = 1024; KKn = 4; }
            int co = j / CK, rem = j % CK;
            int ci = rem % (CK / KKn), khkw = rem / (CK / KKn);
            w23[out_idx] = (_Float16)s[co * CK + ci * KKn + khkw];
        } else {
            int j = i - R1 - R2;
            int o = j / K, rem = j % K;
            int sp = rem / 512, co = rem % 512;
            const float* s = (o < 9) ? (fcs + o * K) : (fci + (o - 9) * K);
            fch[j] = (_Float16)s[co * 169 + sp];
        }
    }
}

// ---------------------------------------------------------------------------
// m = reshape(|h|,3,3)^T; n = max L1 row norm + 1e-4; msc = m / n.
// ---------------------------------------------------------------------------
__global__ void build_m(const float* __restrict__ h, float* __restrict__ msc)
{
    int b = threadIdx.x;
    if (b < 16) {
        float m[9];
#pragma unroll
        for (int i = 0; i < 3; ++i)
#pragma unroll
            for (int j = 0; j < 3; ++j) m[i * 3 + j] = fabsf(h[b * 9 + j * 3 + i]);
        float n = 0.f;
#pragma unroll
        for (int i = 0; i < 3; ++i) {
            float r = m[i * 3] + m[i * 3 + 1] + m[i * 3 + 2];
            n = fmaxf(n, r);
        }
        n += 1e-4f;
        float inv = 1.f / n;
#pragma unroll
        for (int k = 0; k < 9; ++k) msc[b * 9 + k] = m[k] * inv;
    }
}

// ---------------------------------------------------------------------------
// est[b] = inv(msc[b]) @ |ill[b]|
// ---------------------------------------------------------------------------
__global__ void final_est(const float* __restrict__ msc, const float* __restrict__ ill,
                          float* __restrict__ out)
{
    int bidx = threadIdx.x;
    if (bidx < 16) {
        const float* m = msc + bidx * 9;
        float a = m[0], b = m[1], c = m[2];
        float d = m[3], e = m[4], f = m[5];
        float g = m[6], h = m[7], i = m[8];
        float A = e * i - f * h, B = f * g - d * i, C = d * h - e * g;
        float D = c * h - b * i, E = a * i - c * g, F = b * g - a * h;
        float G = b * f - c * e, H = c * d - a * f, I = a * e - b * d;
        float det = a * A + b * B + c * C;
        float inv_det = 1.f / det;
        float x0 = fabsf(ill[bidx * 3 + 0]);
        float x1 = fabsf(ill[bidx * 3 + 1]);
        float x2 = fabsf(ill[bidx * 3 + 2]);
        out[bidx * 3 + 0] = (A * x0 + D * x1 + G * x2) * inv_det;
        out[bidx * 3 + 1] = (B * x0 + E * x1 + H * x2) * inv_det;
        out[bidx * 3 + 2] = (C * x0 + F * x1 + I * x2) * inv_det;
    }
}

extern "C" void kernel_launch(void* const* d_in, const int* in_sizes, int n_in,
                              void* d_out, int out_size, void* d_ws, size_t ws_size,
                              hipStream_t stream)
{
    (void)in_sizes; (void)n_in; (void)out_size; (void)ws_size;
    const float* image = (const float*)d_in[0];
    const float* su_s  = (const float*)d_in[1];
    const float* sv_s  = (const float*)d_in[2];
    const float* c_s   = (const float*)d_in[3];
    const float* w1_s  = (const float*)d_in[4];
    const float* b1_s  = (const float*)d_in[5];
    const float* w2_s  = (const float*)d_in[6];
    const float* b2_s  = (const float*)d_in[7];
    const float* w3_s  = (const float*)d_in[8];
    const float* b3_s  = (const float*)d_in[9];
    const float* fc_s  = (const float*)d_in[10];
    const float* su_i  = (const float*)d_in[11];
    const float* sv_i  = (const float*)d_in[12];
    const float* c_i   = (const float*)d_in[13];
    const float* w1_i  = (const float*)d_in[14];
    const float* b1_i  = (const float*)d_in[15];
    const float* w2_i  = (const float*)d_in[16];
    const float* b2_i  = (const float*)d_in[17];
    const float* w3_i  = (const float*)d_in[18];
    const float* b3_i  = (const float*)d_in[19];
    const float* fc_i  = (const float*)d_in[20];

    // ---- workspace: cumulative pointer arithmetic ONLY ----
    float* W     = (float*)d_ws;
    float* hist  = W;                         // 178608 f
    float* hd    = hist + 178608;             // 144 f
    float* hsum3 = hd + 144;                  // 48 f
    float* msc   = hsum3 + 48;                // 144 f
    float* p2    = msc + 144;                 // 4*16*196*256 = 3211264 f
    float* p3    = p2 + 3211264;              // 2*16*169*512 = 2768896 f
    float* hpart = p3 + 2768896;              // 48*21*4096 = 4128768 f
    _Float16* o1h   = (_Float16*)(hpart + 48 * HSP * 4096);
    _Float16* o2h   = o1h   + 1722368;        // 16*841*128 halfs
    _Float16* o3h   = o2h   + 802816;         // 16*169*512 halfs
    _Float16* fch   = o3h   + 1384448;        // 12*86528 halfs
    _Float16* w2h_s = fch   + 1038336;
    _Float16* w3h_s = w2h_s + 294912;
    _Float16* w2h_i = w3h_s + 524288;
    _Float16* w3h_i = w2h_i + 294912;
    _Float16* w1h_s = w3h_i + 524288;
    _Float16* w1h_i = w1h_s + 12288;

    const int O2_TOT = 16 * 196 * 256;
    const int O3_TOT = 16 * 169 * 512;
    const int FCK = 86528;

    // ---- single weight-prep dispatch ----
    prep_weights<<<1024, 256, 0, stream>>>(w1_s, w1_i, w2_s, w3_s, w2_i, w3_i,
                                           fc_s, fc_i, w1h_s, w2h_s, fch);

    // ================= sensor branch =================
    hipMemsetAsync(hd, 0, 192 * 4, stream);
    hist_mfma<<<dim3(48, HSP), 256, 0, stream>>>(image, su_s, sv_s, c_s, nullptr, hpart);
    reduce_hist<<<dim3(48, 4), 256, 0, stream>>>(hpart, hist, hsum3);
    conv1_mfma<<<dim3(16, 7), 256, 0, stream>>>(hist, hsum3, w1h_s, b1_s, o1h);
    conv_mfma<128, 256, 3, 2, 29, 14, 128, 4, 96><<<dim3(16, 2, 4), 256, 0, stream>>>(o1h, w2h_s, p2);
    reduce_bias_relu_f16<<<784, 256, 0, stream>>>(p2, b2_s, o2h, 256, O2_TOT / 4, 4, O2_TOT);
    conv_mfma<256, 512, 2, 1, 14, 13, 128, 2, 64><<<dim3(16, 4, 2), 256, 0, stream>>>(o2h, w3h_s, p3);
    reduce_bias_relu_f16<<<1024, 256, 0, stream>>>(p3, b3_s, o3h, 512, O3_TOT / 4, 2, O3_TOT);
    fc_mfma<<<169, 256, 0, stream>>>(o3h, fch, hd, 9);
    build_m<<<1, 64, 0, stream>>>(hd, msc);

    // ================= illuminant branch =================
    hipMemsetAsync(hd, 0, 192 * 4, stream);
    hist_mfma<<<dim3(48, HSP), 256, 0, stream>>>(image, su_i, sv_i, c_i, msc, hpart);
    reduce_hist<<<dim3(48, 4), 256, 0, stream>>>(hpart, hist, hsum3);
    conv1_mfma<<<dim3(16, 7), 256, 0, stream>>>(hist, hsum3, w1h_i, b1_i, o1h);
    conv_mfma<128, 256, 3, 2, 29, 14, 128, 4, 96><<<dim3(16, 2, 4), 256, 0, stream>>>(o1h, w2h_i, p2);
    reduce_bias_relu_f16<<<784, 256, 0, stream>>>(p2, b2_i, o2h, 256, O2_TOT / 4, 4, O2_TOT);
    conv_mfma<256, 512, 2, 1, 14, 13, 128, 2, 64><<<dim3(16, 4, 2), 256, 0, stream>>>(o2h, w3h_i, p3);
    reduce_bias_relu_f16<<<1024, 256, 0, stream>>>(p3, b3_i, o3h, 512, O3_TOT / 4, 2, O3_TOT);
    fc_mfma<<<169, 256, 0, stream>>>(o3h, fch + 9 * FCK, hd, 3);
    final_est<<<1, 64, 0, stream>>>(msc, hd, (float*)d_out);
}

// Round 15
// 342.793 us; speedup vs baseline: 1.3251x; 1.0463x over previous
//
#include <hip/hip_runtime.h>

#define P_PIX 22500
#define HB 61
#define HSP 21
#define PPB 1152
#define NCHK 9

typedef float f32x4 __attribute__((ext_vector_type(4)));
typedef _Float16 f16x8 __attribute__((ext_vector_type(8)));
typedef _Float16 f16x4 __attribute__((ext_vector_type(4)));

// ---------------------------------------------------------------------------
// MFMA RGB-uv soft histogram (r14, verified 51.8 us).
// ---------------------------------------------------------------------------
__global__ __launch_bounds__(256) void hist_mfma(
    const float* __restrict__ img, const float* __restrict__ su,
    const float* __restrict__ sv, const float* __restrict__ cw,
    const float* __restrict__ msc, float* __restrict__ hpart)
{
    const int bc = blockIdx.x;
    const int b = bc / 3, c = bc % 3;
    const int split = blockIdx.y;
    const int tid  = threadIdx.x;
    const int wv   = tid >> 6;
    const int lane = tid & 63;
    const int quad = lane >> 4;
    const int mr   = lane & 15;

    __shared__ __align__(16) _Float16 B_lds[8192];
    __shared__ float suu[128], svv[128], sww[128];

    const float sig_u = su[c], sig_v = sv[c];
    const float inv_su2 = 1.f / (sig_u * sig_u);
    const float inv_sv2 = 1.f / (sig_v * sig_v);
    const float cwc = cw[c];
    const float ubin_b = -3.f + 0.1f * (float)lane;
    const float ubin_a = -3.f + 0.1f * (float)(wv * 16 + mr);

    const bool hasM = (msc != nullptr);
    float m00=0,m01=0,m02=0,m10=0,m11=0,m12=0,m20=0,m21=0,m22=0;
    if (hasM) {
        const float* mp = msc + b * 9;
        m00=mp[0]; m01=mp[1]; m02=mp[2];
        m10=mp[3]; m11=mp[4]; m12=mp[5];
        m20=mp[6]; m21=mp[7]; m22=mp[8];
    }

    const int p0   = split * PPB;
    const int pend = min(p0 + PPB, P_PIX);

    f32x4 acc[4];
#pragma unroll
    for (int nt = 0; nt < 4; ++nt) acc[nt] = (f32x4){0.f, 0.f, 0.f, 0.f};

    for (int chunk = 0; chunk < NCHK; ++chunk) {
        __syncthreads();
        if (tid < 128) {
            int px = p0 + chunk * 128 + tid;
            float u = 0.f, v = 0.f, wgt = 0.f;
            if (px < pend) {
                const float* ip = img + (size_t)b * 3 * P_PIX + px;
                float r = ip[0], g = ip[P_PIX], bl = ip[2 * P_PIX];
                if (hasM) {
                    float r2 = m00 * r + m01 * g + m02 * bl;
                    float g2 = m10 * r + m11 * g + m12 * bl;
                    float b2 = m20 * r + m21 * g + m22 * bl;
                    r = r2; g = g2; bl = b2;
                }
                r  = fminf(fmaxf(r, 0.f), 1.f);
                g  = fminf(fmaxf(g, 0.f), 1.f);
                bl = fminf(fmaxf(bl, 0.f), 1.f);
                float Iy = sqrtf(r * r + g * g + bl * bl);
                float lr = __logf(r + 1e-6f);
                float lg = __logf(g + 1e-6f);
                float lb = __logf(bl + 1e-6f);
                if (c == 0)      { u = lr - lg; v = lr - lb; }
                else if (c == 1) { u = lg - lr; v = lg - lb; }
                else             { u = lb - lr; v = lb - lg; }
                wgt = Iy * cwc;
            }
            suu[tid] = u; svv[tid] = v; sww[tid] = wgt;
        }
        __syncthreads();
#pragma unroll
        for (int r = 0; r < 4; ++r) {
            int pg = wv + 4 * r;
            f32x4 v0 = *(const f32x4*)&svv[pg * 8];
            f32x4 v1 = *(const f32x4*)&svv[pg * 8 + 4];
            f16x8 bv;
#pragma unroll
            for (int j = 0; j < 4; ++j) {
                float dv = v0[j] - ubin_b;
                bv[j] = (_Float16)__expf(-dv * dv * inv_sv2);
                float dv1 = v1[j] - ubin_b;
                bv[4 + j] = (_Float16)__expf(-dv1 * dv1 * inv_sv2);
            }
            *(f16x8*)&B_lds[(pg * 64 + lane) * 8] = bv;
        }
        f16x8 af[4];
#pragma unroll
        for (int kk = 0; kk < 4; ++kk) {
            int pxg = kk * 4 + quad;
            f32x4 u0 = *(const f32x4*)&suu[pxg * 8];
            f32x4 u1 = *(const f32x4*)&suu[pxg * 8 + 4];
            f32x4 w0 = *(const f32x4*)&sww[pxg * 8];
            f32x4 w1 = *(const f32x4*)&sww[pxg * 8 + 4];
#pragma unroll
            for (int j = 0; j < 4; ++j) {
                float du = u0[j] - ubin_a;
                af[kk][j] = (_Float16)(__expf(-du * du * inv_su2) * w0[j]);
                float du1 = u1[j] - ubin_a;
                af[kk][4 + j] = (_Float16)(__expf(-du1 * du1 * inv_su2) * w1[j]);
            }
        }
        __syncthreads();
#pragma unroll
        for (int kk = 0; kk < 4; ++kk) {
            int pgq = kk * 4 + quad;
#pragma unroll
            for (int nt = 0; nt < 4; ++nt) {
                f16x8 bvv = *(const f16x8*)&B_lds[(pgq * 64 + nt * 16 + mr) * 8];
                acc[nt] = __builtin_amdgcn_mfma_f32_16x16x32_f16(af[kk], bvv, acc[nt], 0, 0, 0);
            }
        }
    }

    float* hp = hpart + ((size_t)bc * HSP + split) * 4096;
#pragma unroll
    for (int nt = 0; nt < 4; ++nt) {
        int v = nt * 16 + mr;
#pragma unroll
        for (int r = 0; r < 4; ++r) {
            int u = wv * 16 + quad * 4 + r;
            hp[u * 64 + v] = acc[nt][r];
        }
    }
}

// ---------------------------------------------------------------------------
// Sum HSP slabs -> hist; per-(b,c) total -> hsum3.
// ---------------------------------------------------------------------------
__global__ __launch_bounds__(256) void reduce_hist(
    const float* __restrict__ hpart, float* __restrict__ hist,
    float* __restrict__ hsum3)
{
    const int bc = blockIdx.x;
    const int part = blockIdx.y;
    const int tid = threadIdx.x;
    const float* base = hpart + (size_t)bc * HSP * 4096;
    float lsum = 0.f;
#pragma unroll
    for (int t = 0; t < 4; ++t) {
        int idx = part * 1024 + t * 256 + tid;
        int u = idx >> 6, v = idx & 63;
        float s = 0.f;
        for (int sp = 0; sp < HSP; ++sp) s += base[sp * 4096 + idx];
        if (u < HB && v < HB) {
            hist[(size_t)bc * (HB * HB) + u * HB + v] = s;
            lsum += s;
        }
    }
    __shared__ float red[4];
    for (int off = 32; off; off >>= 1) lsum += __shfl_down(lsum, off, 64);
    if ((tid & 63) == 0) red[tid >> 6] = lsum;
    __syncthreads();
    if (tid == 0) atomicAdd(&hsum3[bc], red[0] + red[1] + red[2] + red[3]);
}

// ---------------------------------------------------------------------------
// conv1 implicit-GEMM MFMA, NHWC output.  M-tile 64 -> grid (16,14) = 224
// blocks (was 112 at tile 128; 0.5 blocks/CU starved the machine).
// ---------------------------------------------------------------------------
__global__ __launch_bounds__(256) void conv1_mfma(
    const float* __restrict__ hist, const float* __restrict__ hsum3,
    const _Float16* __restrict__ w1h, const float* __restrict__ bias,
    _Float16* __restrict__ out)
{
    const int b    = blockIdx.x;
    const int m0   = blockIdx.y * 64;
    const int tid  = threadIdx.x;
    const int wv   = tid >> 6;
    const int lane = tid & 63;
    const int quad = lane >> 4;
    const int mr   = lane & 15;

    __shared__ __align__(16) _Float16 A_lds[64 * 96];   // [kg(12)][m(64)][8]

    const float sc = 1.f / (hsum3[b * 3] + hsum3[b * 3 + 1] + hsum3[b * 3 + 2] + 1e-6f);
    const float* inb = hist + (size_t)b * 3 * 3721;

    for (int slot = tid; slot < 768; slot += 256) {
        int m  = slot & 63;
        int kg = slot >> 6;
        int mg = m0 + m;
        bool mok = (mg < 841);
        int oh = mok ? mg / 29 : 0;
        int ow = mok ? mg % 29 : 0;
        const float* pbase = inb + (oh * 2) * 61 + (ow * 2);
        f16x8 av;
#pragma unroll
        for (int j = 0; j < 8; ++j) {
            int k = kg * 8 + j;
            float x = 0.f;
            if (mok && k < 75) {
                int ci = k / 25, r = k % 25;
                int kh = r / 5, kw = r % 5;
                x = pbase[ci * 3721 + kh * 61 + kw] * sc;
            }
            av[j] = (_Float16)x;
        }
        *(f16x8*)&A_lds[(kg * 64 + m) * 8] = av;
    }
    __syncthreads();

    f16x8 wf[3][2];
#pragma unroll
    for (int ks = 0; ks < 3; ++ks)
#pragma unroll
        for (int nt = 0; nt < 2; ++nt) {
            int co = (wv * 2 + nt) * 16 + mr;
            wf[ks][nt] = *(const f16x8*)&w1h[co * 96 + ks * 32 + quad * 8];
        }

    f32x4 acc[4][2];
#pragma unroll
    for (int mt = 0; mt < 4; ++mt)
#pragma unroll
        for (int nt = 0; nt < 2; ++nt) acc[mt][nt] = (f32x4){0.f, 0.f, 0.f, 0.f};

#pragma unroll
    for (int ks = 0; ks < 3; ++ks)
#pragma unroll
        for (int mt = 0; mt < 4; ++mt) {
            f16x8 bv = *(const f16x8*)&A_lds[((ks * 4 + quad) * 64 + mt * 16 + mr) * 8];
#pragma unroll
            for (int nt = 0; nt < 2; ++nt)
                acc[mt][nt] = __builtin_amdgcn_mfma_f32_16x16x32_f16(bv, wf[ks][nt], acc[mt][nt], 0, 0, 0);
        }

#pragma unroll
    for (int mt = 0; mt < 4; ++mt) {
#pragma unroll
        for (int r = 0; r < 4; ++r) {
            int sp = m0 + mt * 16 + quad * 4 + r;
            if (sp >= 841) continue;
#pragma unroll
            for (int nt = 0; nt < 2; ++nt) {
                int co = (wv * 2 + nt) * 16 + mr;
                float y = acc[mt][nt][r] + bias[co];
                out[((size_t)b * 841 + sp) * 128 + co] = (_Float16)fmaxf(y, 0.f);
            }
        }
    }
}

// ---------------------------------------------------------------------------
// conv2/conv3 implicit-GEMM MFMA, NHWC in/out (r12 structure; bigger KSPL
// for >=1.5 blocks/CU; K-split keeps total staging constant).
// ---------------------------------------------------------------------------
template<int CIN, int COUT, int Kk, int S, int IN, int OUT,
         int NPB, int KSPL, int KCH>
__global__ __launch_bounds__(256) void conv_mfma(
    const _Float16* __restrict__ in_h,
    const _Float16* __restrict__ w_h,
    float* __restrict__ out)             // [KSPL][B][OSZ][COUT]
{
    constexpr int KK   = Kk * Kk;
    constexpr int OSZ  = OUT * OUT;
    constexpr int MT   = (OSZ + 15) / 16;
    constexpr int MP   = MT * 16;
    constexpr int KTOT = CIN * KK;
    constexpr int KC   = KTOT / KSPL;
    constexpr int NCHUNK = KC / KCH;
    constexpr int NT   = NPB / 64;
    constexpr int KSN  = KCH / 32;
    constexpr int SLOTS = MP * (KCH / 8);

    const int b   = blockIdx.x;
    const int co0 = blockIdx.y * NPB;
    const int k00 = blockIdx.z * KC;
    const int tid  = threadIdx.x;
    const int wv   = tid >> 6;
    const int lane = tid & 63;
    const int quad = lane >> 4;
    const int mr   = lane & 15;

    __shared__ __align__(16) _Float16 A_lds[MP * KCH];

    const _Float16* inb = in_h + (size_t)b * (IN * IN) * CIN;
    float* outp = out + (size_t)blockIdx.z * gridDim.x * OSZ * COUT;

    f32x4 acc[MT][NT];
#pragma unroll
    for (int mt = 0; mt < MT; ++mt)
#pragma unroll
        for (int nt = 0; nt < NT; ++nt) acc[mt][nt] = (f32x4){0.f, 0.f, 0.f, 0.f};

    for (int ch = 0; ch < NCHUNK; ++ch) {
        const int k0 = k00 + ch * KCH;
        __syncthreads();
        for (int slot = tid; slot < SLOTS; slot += 256) {
            int m  = slot % MP;
            int kg = slot / MP;
            bool mok = (m < OSZ);
            int oh = mok ? m / OUT : 0;
            int ow = mok ? m % OUT : 0;
            int kbase = k0 + kg * 8;
            int khkw = kbase / CIN;
            int ci0  = kbase % CIN;
            int kh = khkw / Kk, kw = khkw % Kk;
            f16x8 av = (f16x8)(_Float16)0.f;
            if (mok)
                av = *(const f16x8*)&inb[((size_t)((oh * S + kh) * IN + (ow * S + kw))) * CIN + ci0];
            *(f16x8*)&A_lds[(kg * MP + m) * 8] = av;
        }
        __syncthreads();
        f16x8 wf[KSN][NT];
#pragma unroll
        for (int ks = 0; ks < KSN; ++ks)
#pragma unroll
            for (int nt = 0; nt < NT; ++nt) {
                int co = co0 + (wv * NT + nt) * 16 + mr;
                wf[ks][nt] = *(const f16x8*)&w_h[(size_t)co * KTOT + k0 + ks * 32 + quad * 8];
            }
#pragma unroll
        for (int ks = 0; ks < KSN; ++ks) {
#pragma unroll
            for (int mt = 0; mt < MT; ++mt) {
                f16x8 bv = *(const f16x8*)&A_lds[((ks * 4 + quad) * MP + mt * 16 + mr) * 8];
#pragma unroll
                for (int nt = 0; nt < NT; ++nt)
                    acc[mt][nt] = __builtin_amdgcn_mfma_f32_16x16x32_f16(bv, wf[ks][nt], acc[mt][nt], 0, 0, 0);
            }
        }
    }

#pragma unroll
    for (int mt = 0; mt < MT; ++mt) {
#pragma unroll
        for (int r = 0; r < 4; ++r) {
            int sp = mt * 16 + quad * 4 + r;
            if (sp >= OSZ) continue;
#pragma unroll
            for (int nt = 0; nt < NT; ++nt) {
                int co = co0 + (wv * NT + nt) * 16 + mr;
                outp[((size_t)b * OSZ + sp) * COUT + co] = acc[mt][nt][r];
            }
        }
    }
}

// ---------------------------------------------------------------------------
// float4 split-K reduce + bias + ReLU -> f16 (NHWC: co = 4i % cout).
// ---------------------------------------------------------------------------
__global__ __launch_bounds__(256) void reduce_bias_relu_f16(
    const float* __restrict__ p, const float* __restrict__ bias,
    _Float16* __restrict__ out, int cout, int total4, int kspl, int total)
{
    for (int i4 = blockIdx.x * 256 + threadIdx.x; i4 < total4; i4 += gridDim.x * 256) {
        f32x4 s = (f32x4){0.f, 0.f, 0.f, 0.f};
        for (int ks = 0; ks < kspl; ++ks)
            s += *(const f32x4*)&p[(size_t)ks * total + i4 * 4];
        f32x4 bb = *(const f32x4*)&bias[(i4 * 4) % cout];
        f16x4 o;
#pragma unroll
        for (int j = 0; j < 4; ++j) o[j] = (_Float16)fmaxf(s[j] + bb[j], 0.f);
        *(f16x4*)&out[(size_t)i4 * 4] = o;
    }
}

// ---------------------------------------------------------------------------
// fc as split-K MFMA (r14, verified).
// ---------------------------------------------------------------------------
__global__ __launch_bounds__(256) void fc_mfma(
    const _Float16* __restrict__ z,     // [16][86528]
    const _Float16* __restrict__ fcw,   // [NO][86528]
    float* __restrict__ out, int NO)
{
    const int tid  = threadIdx.x;
    const int wv   = tid >> 6;
    const int lane = tid & 63;
    const int quad = lane >> 4;
    const int mr   = lane & 15;
    const int kw0  = blockIdx.x * 512 + wv * 128;

    __shared__ float sred[1024];

    f32x4 acc = (f32x4){0.f, 0.f, 0.f, 0.f};
    const bool bok = (mr < NO);
#pragma unroll
    for (int ks = 0; ks < 4; ++ks) {
        int kk = kw0 + ks * 32 + quad * 8;
        f16x8 av = *(const f16x8*)&z[(size_t)mr * 86528 + kk];
        f16x8 bw = (f16x8)(_Float16)0.f;
        if (bok) bw = *(const f16x8*)&fcw[(size_t)mr * 86528 + kk];
        acc = __builtin_amdgcn_mfma_f32_16x16x32_f16(av, bw, acc, 0, 0, 0);
    }
#pragma unroll
    for (int r = 0; r < 4; ++r)
        sred[wv * 256 + (quad * 4 + r) * 16 + mr] = acc[r];
    __syncthreads();
    if (tid < 256) {
        float s = sred[tid] + sred[256 + tid] + sred[512 + tid] + sred[768 + tid];
        int o = tid & 15, b = tid >> 4;
        if (o < NO) atomicAdd(&out[b * NO + o], s);
    }
}

// ---------------------------------------------------------------------------
// ONE weight-prep kernel: zero accumulators (hd/hd2/hsum3a/b), w1 pad,
// w2/w3 NHWC transpose, fc transpose -> f16.
// ---------------------------------------------------------------------------
__global__ __launch_bounds__(256) void prep_weights(
    const float* __restrict__ w1s, const float* __restrict__ w1i,
    const float* __restrict__ w2s, const float* __restrict__ w3s,
    const float* __restrict__ w2i, const float* __restrict__ w3i,
    const float* __restrict__ fcs, const float* __restrict__ fci,
    _Float16* __restrict__ w1h, _Float16* __restrict__ w23,
    _Float16* __restrict__ fch, float* __restrict__ zp)
{
    const int R0 = 384;                 // hd(144)+hd2(144)+hsum3a(48)+hsum3b(48)
    const int R1 = 24576;
    const int N2 = 294912, N3 = 524288;
    const int R2 = 2 * (N2 + N3);
    const int K = 86528;
    const int R3 = 12 * K;
    const int T = R0 + R1 + R2 + R3;
    for (int i = blockIdx.x * 256 + threadIdx.x; i < T; i += gridDim.x * 256) {
        if (i < R0) {
            zp[i] = 0.f;
        } else if (i < R0 + R1) {
            int r0 = i - R0;
            int br = r0 / 12288, r = r0 % 12288;
            int co = r / 96, k = r % 96;
            const float* s = br ? w1i : w1s;
            w1h[r0] = (k < 75) ? (_Float16)s[co * 75 + k] : (_Float16)0.f;
        } else if (i < R0 + R1 + R2) {
            int j = i - R0 - R1;
            int out_idx = j;
            const float* s; int CK, KKn;
            if (j < N2)                { s = w2s; CK = 1152; KKn = 9; }
            else if (j < N2 + N3)      { s = w3s; j -= N2; CK = 1024; KKn = 4; }
            else if (j < 2 * N2 + N3)  { s = w2i; j -= N2 + N3; CK = 1152; KKn = 9; }
            else                       { s = w3i; j -= 2 * N2 + N3; CK = 1024; KKn = 4; }
            int co = j / CK, rem = j % CK;
            int ci = rem % (CK / KKn), khkw = rem / (CK / KKn);
            w23[out_idx] = (_Float16)s[co * CK + ci * KKn + khkw];
        } else {
            int j = i - R0 - R1 - R2;
            int o = j / K, rem = j % K;
            int sp = rem / 512, co = rem % 512;
            const float* s = (o < 9) ? (fcs + o * K) : (fci + (o - 9) * K);
            fch[j] = (_Float16)s[co * 169 + sp];
        }
    }
}

// ---------------------------------------------------------------------------
// m = reshape(|h|,3,3)^T; n = max L1 row norm + 1e-4; msc = m / n.
// ---------------------------------------------------------------------------
__global__ void build_m(const float* __restrict__ h, float* __restrict__ msc)
{
    int b = threadIdx.x;
    if (b < 16) {
        float m[9];
#pragma unroll
        for (int i = 0; i < 3; ++i)
#pragma unroll
            for (int j = 0; j < 3; ++j) m[i * 3 + j] = fabsf(h[b * 9 + j * 3 + i]);
        float n = 0.f;
#pragma unroll
        for (int i = 0; i < 3; ++i) {
            float r = m[i * 3] + m[i * 3 + 1] + m[i * 3 + 2];
            n = fmaxf(n, r);
        }
        n += 1e-4f;
        float inv = 1.f / n;
#pragma unroll
        for (int k = 0; k < 9; ++k) msc[b * 9 + k] = m[k] * inv;
    }
}

// ---------------------------------------------------------------------------
// est[b] = inv(msc[b]) @ |ill[b]|
// ---------------------------------------------------------------------------
__global__ void final_est(const float* __restrict__ msc, const float* __restrict__ ill,
                          float* __restrict__ out)
{
    int bidx = threadIdx.x;
    if (bidx < 16) {
        const float* m = msc + bidx * 9;
        float a = m[0], b = m[1], c = m[2];
        float d = m[3], e = m[4], f = m[5];
        float g = m[6], h = m[7], i = m[8];
        float A = e * i - f * h, B = f * g - d * i, C = d * h - e * g;
        float D = c * h - b * i, E = a * i - c * g, F = b * g - a * h;
        float G = b * f - c * e, H = c * d - a * f, I = a * e - b * d;
        float det = a * A + b * B + c * C;
        float inv_det = 1.f / det;
        float x0 = fabsf(ill[bidx * 3 + 0]);
        float x1 = fabsf(ill[bidx * 3 + 1]);
        float x2 = fabsf(ill[bidx * 3 + 2]);
        out[bidx * 3 + 0] = (A * x0 + D * x1 + G * x2) * inv_det;
        out[bidx * 3 + 1] = (B * x0 + E * x1 + H * x2) * inv_det;
        out[bidx * 3 + 2] = (C * x0 + F * x1 + I * x2) * inv_det;
    }
}

extern "C" void kernel_launch(void* const* d_in, const int* in_sizes, int n_in,
                              void* d_out, int out_size, void* d_ws, size_t ws_size,
                              hipStream_t stream)
{
    (void)in_sizes; (void)n_in; (void)out_size; (void)ws_size;
    const float* image = (const float*)d_in[0];
    const float* su_s  = (const float*)d_in[1];
    const float* sv_s  = (const float*)d_in[2];
    const float* c_s   = (const float*)d_in[3];
    const float* w1_s  = (const float*)d_in[4];
    const float* b1_s  = (const float*)d_in[5];
    const float* w2_s  = (const float*)d_in[6];
    const float* b2_s  = (const float*)d_in[7];
    const float* w3_s  = (const float*)d_in[8];
    const float* b3_s  = (const float*)d_in[9];
    const float* fc_s  = (const float*)d_in[10];
    const float* su_i  = (const float*)d_in[11];
    const float* sv_i  = (const float*)d_in[12];
    const float* c_i   = (const float*)d_in[13];
    const float* w1_i  = (const float*)d_in[14];
    const float* b1_i  = (const float*)d_in[15];
    const float* w2_i  = (const float*)d_in[16];
    const float* b2_i  = (const float*)d_in[17];
    const float* w3_i  = (const float*)d_in[18];
    const float* b3_i  = (const float*)d_in[19];
    const float* fc_i  = (const float*)d_in[20];

    // ---- workspace: cumulative pointer arithmetic ONLY.  hpart/p2/p3
    // share ONE union region (liveness strictly serial, stream-ordered):
    // hpart -> (reduce_hist) -> p2 -> (reduce2) -> p3 -> (reduce3) -> next.
    float* W      = (float*)d_ws;
    float* hist   = W;                        // 178608 f
    float* hd     = hist + 178608;            // 144 (zeroed in prep)
    float* hd2    = hd + 144;                 // 144 (zeroed in prep)
    float* hsum3a = hd2 + 144;                // 48  (zeroed in prep)
    float* hsum3b = hsum3a + 48;              // 48  (zeroed in prep)
    float* msc    = hsum3b + 48;              // 144
    float* U      = msc + 144;                // union: max(hpart 4128768,
                                              //   p2 12*802816=9633792,
                                              //   p3 8*1384448=11075584)
    float* hpart  = U;
    float* p2     = U;
    float* p3     = U;
    _Float16* o1h   = (_Float16*)(U + 11075584);
    _Float16* o2h   = o1h   + 1722368;
    _Float16* o3h   = o2h   + 802816;
    _Float16* fch   = o3h   + 1384448;
    _Float16* w2h_s = fch   + 1038336;
    _Float16* w3h_s = w2h_s + 294912;
    _Float16* w2h_i = w3h_s + 524288;
    _Float16* w3h_i = w2h_i + 294912;
    _Float16* w1h_s = w3h_i + 524288;
    _Float16* w1h_i = w1h_s + 12288;
    // total ~58 MB

    const int O2_TOT = 16 * 196 * 256;
    const int O3_TOT = 16 * 169 * 512;
    const int FCK = 86528;

    prep_weights<<<1024, 256, 0, stream>>>(w1_s, w1_i, w2_s, w3_s, w2_i, w3_i,
                                           fc_s, fc_i, w1h_s, w2h_s, fch, hd);

    // ================= sensor branch =================
    hist_mfma<<<dim3(48, HSP), 256, 0, stream>>>(image, su_s, sv_s, c_s, nullptr, hpart);
    reduce_hist<<<dim3(48, 4), 256, 0, stream>>>(hpart, hist, hsum3a);
    conv1_mfma<<<dim3(16, 14), 256, 0, stream>>>(hist, hsum3a, w1h_s, b1_s, o1h);
    conv_mfma<128, 256, 3, 2, 29, 14, 128, 12, 96><<<dim3(16, 2, 12), 256, 0, stream>>>(o1h, w2h_s, p2);
    reduce_bias_relu_f16<<<784, 256, 0, stream>>>(p2, b2_s, o2h, 256, O2_TOT / 4, 12, O2_TOT);
    conv_mfma<256, 512, 2, 1, 14, 13, 128, 8, 64><<<dim3(16, 4, 8), 256, 0, stream>>>(o2h, w3h_s, p3);
    reduce_bias_relu_f16<<<1024, 256, 0, stream>>>(p3, b3_s, o3h, 512, O3_TOT / 4, 8, O3_TOT);
    fc_mfma<<<169, 256, 0, stream>>>(o3h, fch, hd, 9);
    build_m<<<1, 64, 0, stream>>>(hd, msc);

    // ================= illuminant branch =================
    hist_mfma<<<dim3(48, HSP), 256, 0, stream>>>(image, su_i, sv_i, c_i, msc, hpart);
    reduce_hist<<<dim3(48, 4), 256, 0, stream>>>(hpart, hist, hsum3b);
    conv1_mfma<<<dim3(16, 14), 256, 0, stream>>>(hist, hsum3b, w1h_i, b1_i, o1h);
    conv_mfma<128, 256, 3, 2, 29, 14, 128, 12, 96><<<dim3(16, 2, 12), 256, 0, stream>>>(o1h, w2h_i, p2);
    reduce_bias_relu_f16<<<784, 256, 0, stream>>>(p2, b2_i, o2h, 256, O2_TOT / 4, 12, O2_TOT);
    conv_mfma<256, 512, 2, 1, 14, 13, 128, 8, 64><<<dim3(16, 4, 8), 256, 0, stream>>>(o2h, w3h_i, p3);
    reduce_bias_relu_f16<<<1024, 256, 0, stream>>>(p3, b3_i, o3h, 512, O3_TOT / 4, 8, O3_TOT);
    fc_mfma<<<169, 256, 0, stream>>>(o3h, fch + 9 * FCK, hd2, 3);
    final_est<<<1, 64, 0, stream>>>(msc, hd2, (float*)d_out);
}